// Round 5
// baseline (1294.645 us; speedup 1.0000x reference)
//
#include <hip/hip_runtime.h>

typedef unsigned short ushort_t;
typedef unsigned int uint_t;
typedef __attribute__((ext_vector_type(8))) short short8;
typedef __attribute__((ext_vector_type(4))) float f32x4;

static constexpr int V = 32000, H = 512, HALFD = 256, LSEQ = 1024, BB = 64;

__device__ __forceinline__ ushort_t f2bf(float f) {
    uint_t u = __float_as_uint(f);
    u = (u + 0x7FFFu + ((u >> 16) & 1u)) >> 16;
    return (ushort_t)u;
}
__device__ __forceinline__ float bf2f(ushort_t u) {
    return __uint_as_float(((uint_t)u) << 16);
}
__device__ __forceinline__ float bflo(uint_t u) { return __uint_as_float(u << 16); }
__device__ __forceinline__ float bfhi(uint_t u) { return __uint_as_float(u & 0xffff0000u); }
__device__ __forceinline__ float bfres(float v) { return v - bf2f(f2bf(v)); }

// ---- async global->LDS (width 16); dest = wave-uniform base + lane*16 ------------
typedef const __attribute__((address_space(1))) void* gas_ptr;
typedef __attribute__((address_space(3))) void* las_ptr;
#define GLDS16(g, l) __builtin_amdgcn_global_load_lds((gas_ptr)(g), (las_ptr)(l), 16, 0, 0)

// ---- encoder LDS addressing: packed 64B rows (4x16B chunks), XOR-swizzled --------
// slot(row, chunk) = chunk ^ ((row>>1)&3).  Conflict-free for lid-row frag reads
// AND linear (byte = t*16) for global_load_lds staging with pre-swizzled source.
__device__ __forceinline__ const short8* rd64(const ushort_t* b, int row, int chunk) {
    return (const short8*)(b + row * 32 + (((chunk ^ ((row >> 1) & 3)) & 3) << 3));
}
__device__ __forceinline__ ushort_t* wr64(ushort_t* b, int row, int chunk) {
    return b + row * 32 + (((chunk ^ ((row >> 1) & 3)) & 3) << 3);
}

// ---- scan LDS addressing: 512B / 128B rows, XOR key = (row&7)^((row>>2)&7) -------
// Makes quad-spread b16 dumps (rows 4 apart) AND lid-row b128 frag reads
// conflict-free simultaneously (linear keys can't: 4*delta ≡ {0,4} mod 8).
__device__ __forceinline__ int swz512(int row, int colbyte) {
    int key = (((row & 7) ^ ((row >> 2) & 7)) & 7) << 4;
    return row * 256 + ((colbyte ^ key) >> 1);          // ushort index
}
__device__ __forceinline__ int swz128(int row, int colbyte) {
    int key = (((row & 7) ^ ((row >> 2) & 7)) & 7) << 4;
    return row * 64 + ((colbyte ^ key) >> 1);           // ushort index
}

// ---------------- weight transpose + fp32->bf16 convert: Wt[n][k] = bf16(W[k][n]) --
__global__ void transpose_cvt(const float* __restrict__ W, ushort_t* __restrict__ Wt,
                              int K, int N) {
    __shared__ float tile[32][33];
    int k0 = blockIdx.y * 32, n0 = blockIdx.x * 32;
    int tx = threadIdx.x & 31, ty = threadIdx.x >> 5;   // 256 threads: ty 0..7
    #pragma unroll
    for (int i = 0; i < 32; i += 8)
        tile[ty + i][tx] = W[(size_t)(k0 + ty + i) * N + n0 + tx];
    __syncthreads();
    #pragma unroll
    for (int i = 0; i < 32; i += 8)
        Wt[(size_t)(n0 + ty + i) * K + k0 + tx] = f2bf(tile[tx][ty + i]);
}

// ======================= GEMM 1: t1 = relu(gather(embed,seq) @ w1 + b1) ===========
// B staged via global_load_lds (pre-swizzled source); A gathered fp32, converted,
// written to the swizzled layout directly.
__global__ __launch_bounds__(256) void gemm_ffn1(
        const int* __restrict__ seqp, const float* __restrict__ embed,
        const ushort_t* __restrict__ Bt, const float* __restrict__ bias,
        ushort_t* __restrict__ Cout, int N, int K) {
    __shared__ __align__(16) ushort_t Al[4096];         // 128 rows x 64B (swz)
    __shared__ __align__(16) ushort_t Bl[4096];
    int t = threadIdx.x;
    int m0 = blockIdx.y * 128, n0 = blockIdx.x * 128;
    int lane = t & 63, wid = t >> 6;
    int wm = (wid & 1) * 64, wn = (wid >> 1) * 64;
    int lid = lane & 15, quad = lane >> 4;
    int srow = t >> 2;                                  // staging row 0..63
    int gch = (t & 3) ^ ((t >> 3) & 3);                 // pre-swizzled global chunk

    int tok0 = seqp[m0 + srow];
    int tok1 = seqp[m0 + 64 + srow];
    const float* e0 = embed + (size_t)tok0 * H + (t & 3) * 8;
    const float* e1 = embed + (size_t)tok1 * H + (t & 3) * 8;
    const ushort_t* b0p = Bt + (size_t)(n0 + srow) * K + gch * 8;
    const ushort_t* b1p = Bt + (size_t)(n0 + 64 + srow) * K + gch * 8;
    ushort_t* ldsB = Bl + wid * 512;                    // wave-uniform base
    ushort_t* aw0 = wr64(Al, srow, t & 3);              // +2048 = row+64 (same key)

    f32x4 acc[4][4];
    #pragma unroll
    for (int i = 0; i < 4; ++i)
        #pragma unroll
        for (int j = 0; j < 4; ++j)
            acc[i][j] = (f32x4){0.f, 0.f, 0.f, 0.f};

    for (int k0 = 0; k0 < K; k0 += 32) {
        __syncthreads();                                // prior frag reads done
        GLDS16(b0p + k0, ldsB);
        GLDS16(b1p + k0, ldsB + 2048);
        float4 ea0 = *(const float4*)(e0 + k0);
        float4 eb0 = *(const float4*)(e0 + k0 + 4);
        float4 ea1 = *(const float4*)(e1 + k0);
        float4 eb1 = *(const float4*)(e1 + k0 + 4);
        short8 s0, s1;
        s0[0] = (short)f2bf(ea0.x); s0[1] = (short)f2bf(ea0.y);
        s0[2] = (short)f2bf(ea0.z); s0[3] = (short)f2bf(ea0.w);
        s0[4] = (short)f2bf(eb0.x); s0[5] = (short)f2bf(eb0.y);
        s0[6] = (short)f2bf(eb0.z); s0[7] = (short)f2bf(eb0.w);
        s1[0] = (short)f2bf(ea1.x); s1[1] = (short)f2bf(ea1.y);
        s1[2] = (short)f2bf(ea1.z); s1[3] = (short)f2bf(ea1.w);
        s1[4] = (short)f2bf(eb1.x); s1[5] = (short)f2bf(eb1.y);
        s1[6] = (short)f2bf(eb1.z); s1[7] = (short)f2bf(eb1.w);
        *(short8*)aw0 = s0;
        *(short8*)(aw0 + 2048) = s1;
        __syncthreads();                                // drains vmcnt + lds writes
        short8 af[4], bfr[4];
        #pragma unroll
        for (int i = 0; i < 4; ++i) af[i] = *rd64(Al, wm + i * 16 + lid, quad);
        #pragma unroll
        for (int i = 0; i < 4; ++i) bfr[i] = *rd64(Bl, wn + i * 16 + lid, quad);
        #pragma unroll
        for (int mt = 0; mt < 4; ++mt)
            #pragma unroll
            for (int nt = 0; nt < 4; ++nt)
                acc[mt][nt] = __builtin_amdgcn_mfma_f32_16x16x32_bf16(
                    af[mt], bfr[nt], acc[mt][nt], 0, 0, 0);
    }
    #pragma unroll
    for (int mt = 0; mt < 4; ++mt)
        #pragma unroll
        for (int nt = 0; nt < 4; ++nt)
            #pragma unroll
            for (int rg = 0; rg < 4; ++rg) {
                int row = m0 + wm + mt * 16 + quad * 4 + rg;
                int col = n0 + wn + nt * 16 + lid;
                float v = fmaxf(acc[mt][nt][rg] + bias[col], 0.f);
                Cout[(size_t)row * N + col] = f2bf(v);
            }
}

// ======================= GEMM 2: x = t1 @ w2 + b2 + gather(embed,seq) =============
// Both A and B staged via global_load_lds with pre-swizzled sources.
__global__ __launch_bounds__(256) void gemm_ffn2(
        const ushort_t* __restrict__ A, const ushort_t* __restrict__ Bt,
        const float* __restrict__ bias, const int* __restrict__ seqp,
        const float* __restrict__ embed, ushort_t* __restrict__ Cout,
        int N, int K) {
    __shared__ __align__(16) ushort_t Al[4096];
    __shared__ __align__(16) ushort_t Bl[4096];
    int t = threadIdx.x;
    int m0 = blockIdx.y * 128, n0 = blockIdx.x * 128;
    int lane = t & 63, wid = t >> 6;
    int wm = (wid & 1) * 64, wn = (wid >> 1) * 64;
    int lid = lane & 15, quad = lane >> 4;
    int srow = t >> 2;
    int gch = (t & 3) ^ ((t >> 3) & 3);

    const ushort_t* a0p = A + (size_t)(m0 + srow) * K + gch * 8;
    const ushort_t* a1p = A + (size_t)(m0 + 64 + srow) * K + gch * 8;
    const ushort_t* b0p = Bt + (size_t)(n0 + srow) * K + gch * 8;
    const ushort_t* b1p = Bt + (size_t)(n0 + 64 + srow) * K + gch * 8;
    ushort_t* ldsA = Al + wid * 512;
    ushort_t* ldsB = Bl + wid * 512;

    f32x4 acc[4][4];
    #pragma unroll
    for (int i = 0; i < 4; ++i)
        #pragma unroll
        for (int j = 0; j < 4; ++j)
            acc[i][j] = (f32x4){0.f, 0.f, 0.f, 0.f};

    for (int k0 = 0; k0 < K; k0 += 32) {
        __syncthreads();
        GLDS16(a0p + k0, ldsA);
        GLDS16(a1p + k0, ldsA + 2048);
        GLDS16(b0p + k0, ldsB);
        GLDS16(b1p + k0, ldsB + 2048);
        __syncthreads();
        short8 af[4], bfr[4];
        #pragma unroll
        for (int i = 0; i < 4; ++i) af[i] = *rd64(Al, wm + i * 16 + lid, quad);
        #pragma unroll
        for (int i = 0; i < 4; ++i) bfr[i] = *rd64(Bl, wn + i * 16 + lid, quad);
        #pragma unroll
        for (int mt = 0; mt < 4; ++mt)
            #pragma unroll
            for (int nt = 0; nt < 4; ++nt)
                acc[mt][nt] = __builtin_amdgcn_mfma_f32_16x16x32_bf16(
                    af[mt], bfr[nt], acc[mt][nt], 0, 0, 0);
    }
    #pragma unroll
    for (int mt = 0; mt < 4; ++mt)
        #pragma unroll
        for (int rg = 0; rg < 4; ++rg) {
            int row = m0 + wm + mt * 16 + quad * 4 + rg;
            int tok = seqp[row];
            const float* erow = embed + (size_t)tok * H;
            #pragma unroll
            for (int nt = 0; nt < 4; ++nt) {
                int col = n0 + wn + nt * 16 + lid;
                float v = acc[mt][nt][rg] + bias[col] + erow[col];
                Cout[(size_t)row * N + col] = f2bf(v);
            }
        }
}

// ====== fused projections: [ks|ke] = h @ [sem_w|epi_w] + b  (Bt rows concat) ======
__global__ __launch_bounds__(256) void gemm_proj(
        const ushort_t* __restrict__ A, const ushort_t* __restrict__ Bt,
        const float* __restrict__ biasS, const float* __restrict__ biasE,
        ushort_t* __restrict__ outS, ushort_t* __restrict__ outE, int K) {
    __shared__ __align__(16) ushort_t Al[4096];
    __shared__ __align__(16) ushort_t Bl[4096];
    int t = threadIdx.x;
    int m0 = blockIdx.y * 128, n0 = blockIdx.x * 128;   // n0 in 0..384
    int lane = t & 63, wid = t >> 6;
    int wm = (wid & 1) * 64, wn = (wid >> 1) * 64;
    int lid = lane & 15, quad = lane >> 4;
    int srow = t >> 2;
    int gch = (t & 3) ^ ((t >> 3) & 3);

    const ushort_t* a0p = A + (size_t)(m0 + srow) * K + gch * 8;
    const ushort_t* a1p = A + (size_t)(m0 + 64 + srow) * K + gch * 8;
    const ushort_t* b0p = Bt + (size_t)(n0 + srow) * K + gch * 8;
    const ushort_t* b1p = Bt + (size_t)(n0 + 64 + srow) * K + gch * 8;
    ushort_t* ldsA = Al + wid * 512;
    ushort_t* ldsB = Bl + wid * 512;

    f32x4 acc[4][4];
    #pragma unroll
    for (int i = 0; i < 4; ++i)
        #pragma unroll
        for (int j = 0; j < 4; ++j)
            acc[i][j] = (f32x4){0.f, 0.f, 0.f, 0.f};

    for (int k0 = 0; k0 < K; k0 += 32) {
        __syncthreads();
        GLDS16(a0p + k0, ldsA);
        GLDS16(a1p + k0, ldsA + 2048);
        GLDS16(b0p + k0, ldsB);
        GLDS16(b1p + k0, ldsB + 2048);
        __syncthreads();
        short8 af[4], bfr[4];
        #pragma unroll
        for (int i = 0; i < 4; ++i) af[i] = *rd64(Al, wm + i * 16 + lid, quad);
        #pragma unroll
        for (int i = 0; i < 4; ++i) bfr[i] = *rd64(Bl, wn + i * 16 + lid, quad);
        #pragma unroll
        for (int mt = 0; mt < 4; ++mt)
            #pragma unroll
            for (int nt = 0; nt < 4; ++nt)
                acc[mt][nt] = __builtin_amdgcn_mfma_f32_16x16x32_bf16(
                    af[mt], bfr[nt], acc[mt][nt], 0, 0, 0);
    }
    #pragma unroll
    for (int mt = 0; mt < 4; ++mt)
        #pragma unroll
        for (int nt = 0; nt < 4; ++nt)
            #pragma unroll
            for (int rg = 0; rg < 4; ++rg) {
                int row = m0 + wm + mt * 16 + quad * 4 + rg;
                int col = n0 + wn + nt * 16 + lid;   // wave-uniform half selection
                if (col < 256)
                    outS[(size_t)row * HALFD + col] = f2bf(acc[mt][nt][rg] + biasS[col]);
                else
                    outE[(size_t)row * HALFD + col - 256] =
                        f2bf(acc[mt][nt][rg] + biasE[col - 256]);
            }
}

// ---------------- LayerNorm over H=512 (bf16 in-place), one wave per row ----------
__global__ void ln_kernel(ushort_t* X, const float* __restrict__ g,
                          const float* __restrict__ bta) {
    int row = blockIdx.x * 4 + (threadIdx.x >> 6);
    int lane = threadIdx.x & 63;
    ushort_t* xr = X + (size_t)row * H + lane * 8;
    short8 xv = *(short8*)xr;
    float x[8];
    #pragma unroll
    for (int j = 0; j < 8; ++j) x[j] = bf2f((ushort_t)xv[j]);
    float s = 0.f, ss = 0.f;
    #pragma unroll
    for (int j = 0; j < 8; ++j) { s += x[j]; ss += x[j] * x[j]; }
    #pragma unroll
    for (int d = 1; d < 64; d <<= 1) { s += __shfl_xor(s, d); ss += __shfl_xor(ss, d); }
    float mu = s * (1.f / 512.f);
    float var = ss * (1.f / 512.f) - mu * mu;
    float rstd = rsqrtf(var + 1e-5f);
    float4 g0 = *(const float4*)(g + lane * 8);
    float4 g1 = *(const float4*)(g + lane * 8 + 4);
    float4 b0 = *(const float4*)(bta + lane * 8);
    float4 b1 = *(const float4*)(bta + lane * 8 + 4);
    float gg[8] = {g0.x, g0.y, g0.z, g0.w, g1.x, g1.y, g1.z, g1.w};
    float bb[8] = {b0.x, b0.y, b0.z, b0.w, b1.x, b1.y, b1.z, b1.w};
    short8 o;
    #pragma unroll
    for (int j = 0; j < 8; ++j)
        o[j] = (short)f2bf((x[j] - mu) * rstd * gg[j] + bb[j]);
    *(short8*)xr = o;
}

// ---------------- beta[row] = sum(k^2) + 1e-6 (bf16 input), one wave per row ------
__global__ void beta_kernel(const ushort_t* __restrict__ k, float* __restrict__ beta) {
    int row = blockIdx.x * 4 + (threadIdx.x >> 6);
    int lane = threadIdx.x & 63;
    ushort4 a = *(const ushort4*)(k + (size_t)row * HALFD + lane * 4);
    float ax = bf2f(a.x), ay = bf2f(a.y), az = bf2f(a.z), aw = bf2f(a.w);
    float s = ax * ax + ay * ay + az * az + aw * aw;
    #pragma unroll
    for (int d = 1; d < 64; d <<= 1) s += __shfl_xor(s, d);
    if (lane == 0) beta[row] = s + 1e-6f;
}

// ================= chunked delta-rule: Tinv precompute (barrier-free fsub) ========
__global__ __launch_bounds__(256) void tinv_kernel(
        const ushort_t* __restrict__ ks, const ushort_t* __restrict__ ke,
        const float* __restrict__ beta_s, const float* __restrict__ beta_e,
        ushort_t* __restrict__ Dg) {
    __shared__ __align__(16) ushort_t Kl[64][280];
    __shared__ __align__(16) ushort_t LmT[4][64][66];   // LmT[pp][j][i] = L[i][j]
    __shared__ float betsl[4][64];

    int t = threadIdx.x;
    int lane = t & 63, wv = t >> 6;
    int lid = lane & 15, quad = lane >> 4;
    int blk0 = blockIdx.x * 4;
    const float invL = 1.0f / 1024.0f;

    for (int pp = 0; pp < 4; ++pp) {
        int p = blk0 + pp;
        int ch = p & 15, bm = p >> 4;
        int mat = bm & 1, b = bm >> 1;
        const ushort_t* Kp = (mat ? ke : ks) + ((size_t)b * LSEQ + ch * 64) * HALFD;
        const float* Bp = (mat ? beta_e : beta_s) + (size_t)b * LSEQ + ch * 64;

        __syncthreads();                    // Kl free (prev pp's MFMA reads done)
        {   // stage K chunk (64 x 256 bf16)
            int j = t >> 2, c0 = (t & 3) * 64;
            const ushort_t* src = Kp + (size_t)j * HALFD + c0;
            #pragma unroll
            for (int x = 0; x < 8; ++x)
                *(short8*)&Kl[j][c0 + x * 8] = *(const short8*)(src + x * 8);
        }
        if (t < 64) betsl[pp][t] = Bp[t];
        __syncthreads();

        // G = K K^T; wave wv owns rows wv*16..+16
        f32x4 g[4];
        #pragma unroll
        for (int i = 0; i < 4; ++i) g[i] = (f32x4){0.f, 0.f, 0.f, 0.f};
        #pragma unroll
        for (int kc = 0; kc < 8; ++kc) {
            short8 af = *(const short8*)&Kl[wv * 16 + lid][kc * 32 + quad * 8];
            #pragma unroll
            for (int nt = 0; nt < 4; ++nt) {
                short8 bq = *(const short8*)&Kl[nt * 16 + lid][kc * 32 + quad * 8];
                g[nt] = __builtin_amdgcn_mfma_f32_16x16x32_bf16(af, bq, g[nt], 0, 0, 0);
            }
        }
        #pragma unroll
        for (int nt = 0; nt < 4; ++nt)
            #pragma unroll
            for (int rg = 0; rg < 4; ++rg) {
                int i = wv * 16 + quad * 4 + rg;     // row of L
                int j = nt * 16 + lid;               // col of L
                int s = ch * 64 + i;
                float wgt = mat ? (float)(s + 1) * invL : 1.0f;
                if (s >= 1023) wgt = 0.f;            // padding step
                float wb = wgt / betsl[pp][i];
                LmT[pp][j][i] = f2bf((j < i) ? g[nt][rg] * wb : 0.f);
            }
    }
    __syncthreads();                        // all LmT ready

    // barrier-free fsub: wave wv owns problem blk0+wv; lane owns column `lane`
    const ushort_t (*Lp)[66] = LmT[wv];
    float a[64];
    #pragma unroll
    for (int x = 0; x < 32; ++x) {          // a[i] = -L[i][lane] = -LmT[lane][i]
        uint_t u = *(const uint_t*)&Lp[lane][x * 2];
        a[x * 2]     = -bflo(u);
        a[x * 2 + 1] = -bfhi(u);
    }
    #pragma unroll
    for (int j = 0; j < 63; ++j) {
        float dj = a[j];
        const ushort_t* rowj = Lp[j];
        #pragma unroll
        for (int ii = (j + 1) & ~1; ii < 64; ii += 2) {
            uint_t u = *(const uint_t*)&rowj[ii];    // wave-uniform broadcast
            if (ii > j) a[ii] -= bflo(u) * dj;
            a[ii + 1]        -= bfhi(u) * dj;
        }
    }
    size_t pbase = (size_t)(blk0 + wv) * 4096;
    #pragma unroll
    for (int i = 0; i < 64; ++i)
        Dg[pbase + (size_t)i * 64 + lane] = f2bf(a[i]);
}

// ================= chunked delta-rule scan (MFMA, XOR-swizzled LDS) ===============
// r3 structure (plain b16 dumps) + swz512/swz128 addressing: dumps, frag reads and
// Kt-build are all bank-conflict-free (r4 post-mortem: the 16.5M conflicts were the
// quad-row-aliased b16 dumps, NOT the frag reads; odd-slot padding can't fix rows
// 8 apart at 16B-aligned strides -> XOR keyed on (row&7)^((row>>2)&7)).
__global__ __launch_bounds__(512) void scan_kernel(
        const ushort_t* __restrict__ ks, const ushort_t* __restrict__ ke,
        const float* __restrict__ beta_s, const float* __restrict__ beta_e,
        const ushort_t* __restrict__ Dg, float* __restrict__ c) {
    int blk = blockIdx.x;
    int b = blk >> 2, mat = (blk >> 1) & 1, half = blk & 1;
    const ushort_t* Kp = (mat ? ke : ks) + (size_t)b * LSEQ * HALFD;
    const float* Bp = (mat ? beta_e : beta_s) + (size_t)b * LSEQ;
    const ushort_t* Dp = Dg + (size_t)(b * 2 + mat) * 16 * 4096;

    __shared__ __align__(16) ushort_t Kl[16384];        // 64 rows x 512B (swz512)
    __shared__ __align__(16) ushort_t MK[32768];        // Ml 128x512B | Kt 256x128B
    __shared__ __align__(16) ushort_t RHSl[8192];       // 128 rows x 128B (swz128)
    __shared__ __align__(16) ushort_t Ul[8192];         // 128 rows x 128B (swz128)
    __shared__ __align__(16) ushort_t Dl[64][72];       // Tinv - I (odd 9-slot rows)
    __shared__ float betc[64];

    int t = threadIdx.x;
    int lane = t & 63, wid = t >> 6;
    int lid = lane & 15, quad = lane >> 4;
    int wm  = (wid & 1) * 64, wn  = (wid >> 1) * 64;    // GEMM3/M org: 128x256 tile
    int wm1 = (wid & 1) * 64, wn1 = (wid >> 1) * 16;    // GEMM1/2 org: 128x64 tile

    f32x4 acc[4][4];
    #pragma unroll
    for (int i = 0; i < 4; ++i)
        #pragma unroll
        for (int j = 0; j < 4; ++j)
            acc[i][j] = (f32x4){0.f, 0.f, 0.f, 0.f};

    // K staging: thread t -> row sj, 4 x short8 at bytes (t&7)*16 + x*128
    int sj = t >> 3, scb = (t & 7) * 16;
    short8 pf[4];
    {
        const ushort_t* kr = Kp + (size_t)sj * HALFD + (t & 7) * 8;
        #pragma unroll
        for (int x = 0; x < 4; ++x) pf[x] = *(const short8*)(kr + x * 64);
    }
    short8 dpf = *(const short8*)(Dp + t * 8);
    float bpf = (t < 64) ? Bp[t] : 0.f;
    const float invL = 1.0f / 1024.0f;

    for (int ch = 0; ch < 16; ++ch) {
        __syncthreads();                       // F: prior-chunk LDS reads done
        #pragma unroll
        for (int x = 0; x < 4; ++x)
            *(short8*)&Kl[swz512(sj, scb + x * 128)] = pf[x];
        *(short8*)&Dl[t >> 3][(t & 7) * 8] = dpf;
        if (t < 64) betc[t] = bpf;
        // M_hi -> Ml
        #pragma unroll
        for (int mt = 0; mt < 4; ++mt)
            #pragma unroll
            for (int nt = 0; nt < 4; ++nt)
                #pragma unroll
                for (int rg = 0; rg < 4; ++rg)
                    MK[swz512(wm + mt * 16 + quad * 4 + rg, (wn + nt * 16 + lid) * 2)] =
                        f2bf(acc[mt][nt][rg]);
        // prefetch next chunk
        int nch = (ch + 1 < 16) ? ch + 1 : 15;
        {
            const ushort_t* kr = Kp + ((size_t)nch * 64 + sj) * HALFD + (t & 7) * 8;
            #pragma unroll
            for (int x = 0; x < 4; ++x) pf[x] = *(const short8*)(kr + x * 64);
            dpf = *(const short8*)(Dp + (size_t)nch * 4096 + t * 8);
            if (t < 64) bpf = Bp[nch * 64 + t];
        }
        __syncthreads();                       // A

        // GEMM1 hi: P0^T[r,i] += sum_c Mhi[r,c] K[i,c]
        f32x4 p0[4];
        #pragma unroll
        for (int i = 0; i < 4; ++i) p0[i] = (f32x4){0.f, 0.f, 0.f, 0.f};
        #pragma unroll
        for (int kc = 0; kc < 8; ++kc) {
            short8 bq = *(const short8*)&Kl[swz512(wn1 + lid, kc * 64 + quad * 16)];
            #pragma unroll
            for (int mt = 0; mt < 4; ++mt) {
                short8 aq = *(const short8*)&MK[swz512(wm1 + mt * 16 + lid,
                                                       kc * 64 + quad * 16)];
                p0[mt] = __builtin_amdgcn_mfma_f32_16x16x32_bf16(aq, bq, p0[mt], 0, 0, 0);
            }
        }
        __syncthreads();                       // B: Ml(hi) reads done
        // M_lo -> Ml
        #pragma unroll
        for (int mt = 0; mt < 4; ++mt)
            #pragma unroll
            for (int nt = 0; nt < 4; ++nt)
                #pragma unroll
                for (int rg = 0; rg < 4; ++rg)
                    MK[swz512(wm + mt * 16 + quad * 4 + rg, (wn + nt * 16 + lid) * 2)] =
                        f2bf(bfres(acc[mt][nt][rg]));
        __syncthreads();                       // C
        // GEMM1 lo
        #pragma unroll
        for (int kc = 0; kc < 8; ++kc) {
            short8 bq = *(const short8*)&Kl[swz512(wn1 + lid, kc * 64 + quad * 16)];
            #pragma unroll
            for (int mt = 0; mt < 4; ++mt) {
                short8 aq = *(const short8*)&MK[swz512(wm1 + mt * 16 + lid,
                                                       kc * 64 + quad * 16)];
                p0[mt] = __builtin_amdgcn_mfma_f32_16x16x32_bf16(aq, bq, p0[mt], 0, 0, 0);
            }
        }
        // RHS: rhs[r,i] = w_i*k_i[hr] - (w_i/beta_i)*P0^T[r,i]
        int iB = wn1 + lid;
        int s = ch * 64 + iB;
        float wgt = mat ? (float)(s + 1) * invL : 1.0f;
        if (s >= 1023) wgt = 0.f;
        float wb = wgt / betc[iB];
        float rhsf[4][4];
        #pragma unroll
        for (int mt = 0; mt < 4; ++mt)
            #pragma unroll
            for (int rg = 0; rg < 4; ++rg) {
                int r = wm1 + mt * 16 + quad * 4 + rg;
                float kv = bf2f(Kl[swz512(iB, (half * 128 + r) * 2)]);
                float rv = wgt * kv - wb * p0[mt][rg];
                rhsf[mt][rg] = rv;
                RHSl[swz128(r, iB * 2)] = f2bf(rv);
            }
        __syncthreads();                       // D: RHS ready; Ml region free

        // build Kt[c][j] = K[j][c] into the (free) Ml region
        {
            int c0b = wid * 64;                // col-block byte base in K row
            #pragma unroll
            for (int rr = 0; rr < 4; ++rr) {
                short8 kv8 = *(const short8*)&Kl[swz512(lane, c0b + rr * 16)];
                #pragma unroll
                for (int x = 0; x < 8; ++x)
                    MK[swz128(wid * 32 + rr * 8 + x, lane * 2)] = (ushort_t)kv8[x];
            }
        }
        // GEMM2: corr[r,j] = sum_j' RHS^T[r,j'] * D[j,j']
        f32x4 uf[4];
        #pragma unroll
        for (int i = 0; i < 4; ++i) uf[i] = (f32x4){0.f, 0.f, 0.f, 0.f};
        #pragma unroll
        for (int kc = 0; kc < 2; ++kc) {
            short8 bq = *(const short8*)&Dl[wn1 + lid][kc * 32 + quad * 8];
            #pragma unroll
            for (int mt = 0; mt < 4; ++mt) {
                short8 aq = *(const short8*)&RHSl[swz128(wm1 + mt * 16 + lid,
                                                         kc * 64 + quad * 16)];
                uf[mt] = __builtin_amdgcn_mfma_f32_16x16x32_bf16(aq, bq, uf[mt], 0, 0, 0);
            }
        }
        // u = corr + RHS (exact fp32 RHS from regs; frag positions identical)
        #pragma unroll
        for (int mt = 0; mt < 4; ++mt)
            #pragma unroll
            for (int rg = 0; rg < 4; ++rg) {
                int r = wm1 + mt * 16 + quad * 4 + rg;
                Ul[swz128(r, iB * 2)] = f2bf(uf[mt][rg] + rhsf[mt][rg]);
            }
        __syncthreads();                       // E: Kt + U(hi) ready
        // GEMM3 hi: M += Uhi^T * K
        #pragma unroll
        for (int kc = 0; kc < 2; ++kc) {
            short8 bq4[4];
            #pragma unroll
            for (int nt = 0; nt < 4; ++nt)
                bq4[nt] = *(const short8*)&MK[swz128(wn + nt * 16 + lid,
                                                     kc * 64 + quad * 16)];
            #pragma unroll
            for (int mt = 0; mt < 4; ++mt) {
                short8 aq = *(const short8*)&Ul[swz128(wm + mt * 16 + lid,
                                                       kc * 64 + quad * 16)];
                #pragma unroll
                for (int nt = 0; nt < 4; ++nt)
                    acc[mt][nt] = __builtin_amdgcn_mfma_f32_16x16x32_bf16(
                        aq, bq4[nt], acc[mt][nt], 0, 0, 0);
            }
        }
        __syncthreads();                       // E2: Ul(hi) reads done
        #pragma unroll
        for (int mt = 0; mt < 4; ++mt)
            #pragma unroll
            for (int rg = 0; rg < 4; ++rg) {
                int r = wm1 + mt * 16 + quad * 4 + rg;
                float u = uf[mt][rg] + rhsf[mt][rg];
                Ul[swz128(r, iB * 2)] = f2bf(bfres(u));
            }
        __syncthreads();                       // E3
        // GEMM3 lo
        #pragma unroll
        for (int kc = 0; kc < 2; ++kc) {
            short8 bq4[4];
            #pragma unroll
            for (int nt = 0; nt < 4; ++nt)
                bq4[nt] = *(const short8*)&MK[swz128(wn + nt * 16 + lid,
                                                     kc * 64 + quad * 16)];
            #pragma unroll
            for (int mt = 0; mt < 4; ++mt) {
                short8 aq = *(const short8*)&Ul[swz128(wm + mt * 16 + lid,
                                                       kc * 64 + quad * 16)];
                #pragma unroll
                for (int nt = 0; nt < 4; ++nt)
                    acc[mt][nt] = __builtin_amdgcn_mfma_f32_16x16x32_bf16(
                        aq, bq4[nt], acc[mt][nt], 0, 0, 0);
            }
        }
    }

    // final matvec: c[hr] = sum_c M[hr,c] * k[1023][c]  (k[1023] = Kl row 63)
    __syncthreads();
    float* vsc = (float*)RHSl;                 // 4 x 128 scratch
    float kvv[4];
    #pragma unroll
    for (int nt = 0; nt < 4; ++nt)
        kvv[nt] = bf2f(Kl[swz512(63, (wn + nt * 16 + lid) * 2)]);
    #pragma unroll
    for (int mt = 0; mt < 4; ++mt)
        #pragma unroll
        for (int rg = 0; rg < 4; ++rg) {
            float p = acc[mt][0][rg] * kvv[0] + acc[mt][1][rg] * kvv[1]
                    + acc[mt][2][rg] * kvv[2] + acc[mt][3][rg] * kvv[3];
            p += __shfl_xor(p, 1); p += __shfl_xor(p, 2);
            p += __shfl_xor(p, 4); p += __shfl_xor(p, 8);
            if (lid == 0)
                vsc[(wid >> 1) * 128 + wm + mt * 16 + quad * 4 + rg] = p;
        }
    __syncthreads();
    if (t < 128) {
        float sum = vsc[t] + vsc[128 + t] + vsc[256 + t] + vsc[384 + t];
        c[(size_t)b * 512 + mat * 256 + half * 128 + t] = sum;
    }
}

// ---------------- output GEMM: out[64x32000] = c[64x512] @ W[512x32000] + b -------
__global__ __launch_bounds__(512) void out_gemm(
        const float* __restrict__ c, const float* __restrict__ W,
        const float* __restrict__ bias, float* __restrict__ out) {
    __shared__ __align__(16) float cl[16][512];
    int t = threadIdx.x;
    int lane = t & 63, w = t >> 6;                    // 8 waves
    int cb = blockIdx.x * 256;                        // 125*256 = 32000
    int rb = blockIdx.y * 16;                         // 4*16 = 64 rows

    #pragma unroll
    for (int i = 0; i < 4; ++i) {
        int idx = t + i * 512;                        // float4 index
        int row = idx >> 7, c4 = (idx & 127) * 4;
        *(float4*)&cl[row][c4] = *(const float4*)(c + (size_t)(rb + row) * 512 + c4);
    }
    __syncthreads();

    const float* wp = W + cb + lane * 4;
    int r0 = w * 2;
    f32x4 a0 = (f32x4){0.f, 0.f, 0.f, 0.f};
    f32x4 a1 = (f32x4){0.f, 0.f, 0.f, 0.f};

    #pragma unroll 2
    for (int k = 0; k < 512; k += 4) {
        f32x4 w0 = *(const f32x4*)(wp + (size_t)(k + 0) * V);
        f32x4 w1 = *(const f32x4*)(wp + (size_t)(k + 1) * V);
        f32x4 w2 = *(const f32x4*)(wp + (size_t)(k + 2) * V);
        f32x4 w3 = *(const f32x4*)(wp + (size_t)(k + 3) * V);
        f32x4 ca = *(const f32x4*)&cl[r0][k];
        f32x4 cb4 = *(const f32x4*)&cl[r0 + 1][k];
        a0 += ca[0] * w0; a0 += ca[1] * w1; a0 += ca[2] * w2; a0 += ca[3] * w3;
        a1 += cb4[0] * w0; a1 += cb4[1] * w1; a1 += cb4[2] * w2; a1 += cb4[3] * w3;
    }
    f32x4 bv = *(const f32x4*)(bias + cb + lane * 4);
    *(f32x4*)(out + (size_t)(rb + r0) * V + cb + lane * 4) = a0 + bv;
    *(f32x4*)(out + (size_t)(rb + r0 + 1) * V + cb + lane * 4) = a1 + bv;
}

// ---------------- launch ----------------------------------------------------------
extern "C" void kernel_launch(void* const* d_in, const int* in_sizes, int n_in,
                              void* d_out, int out_size, void* d_ws, size_t ws_size,
                              hipStream_t stream) {
    const int*   seq    = (const int*)d_in[0];
    const float* embed  = (const float*)d_in[1];
    const float* ff_w1  = (const float*)d_in[2];
    const float* ff_b1  = (const float*)d_in[3];
    const float* ff_w2  = (const float*)d_in[4];
    const float* ff_b2  = (const float*)d_in[5];
    const float* ln_g   = (const float*)d_in[6];
    const float* ln_b   = (const float*)d_in[7];
    const float* sem_w  = (const float*)d_in[8];
    const float* sem_b  = (const float*)d_in[9];
    const float* epi_w  = (const float*)d_in[10];
    const float* epi_b  = (const float*)d_in[11];
    const float* out_w  = (const float*)d_in[12];
    const float* out_b  = (const float*)d_in[13];
    float* outp = (float*)d_out;

    const int ML = BB * LSEQ;                         // 65536 rows
    int RCH;
    if      (ws_size >= 271712256ull) RCH = 65536;    // 1 chunk
    else if (ws_size >= 120717312ull) RCH = 16384;    // 4 chunks
    else                              RCH = 8192;     // 8 chunks (95,551,488 proven)

    char* w = (char*)d_ws;
    size_t off = 0;
    ushort_t* ks_bf = (ushort_t*)(w + off); off += 33554432;          // 65536x256 bf16
    ushort_t* ke_bf = (ushort_t*)(w + off); off += 33554432;
    ushort_t* ebc   = (ushort_t*)(w + off); off += (size_t)RCH * 512 * 2;   // x/h chunk
    ushort_t* t1c   = (ushort_t*)(w + off); off += (size_t)RCH * 1024 * 2;  // relu chunk
    ushort_t* w1t   = (ushort_t*)(w + off); off += 1048576;
    ushort_t* w2t   = (ushort_t*)(w + off); off += 1048576;
    ushort_t* semt  = (ushort_t*)(w + off); off += 262144;            // semt|epit adjacent
    ushort_t* epit  = (ushort_t*)(w + off); off += 262144;
    float*    bet_s = (float*)(w + off);    off += 262144;
    float*    bet_e = (float*)(w + off);    off += 262144;
    float*    cbuf  = (float*)(w + off);    off += 131072;
    // Tinv-I storage (2048 x 64 x 64 bf16 = 16.8 MB) reuses encoder chunk region.
    ushort_t* Dbuf  = ebc;
    (void)t1c;

    // weight prep (bf16 + transpose)
    transpose_cvt<<<dim3(1024 / 32, 512 / 32), 256, 0, stream>>>(ff_w1, w1t, 512, 1024);
    transpose_cvt<<<dim3(512 / 32, 1024 / 32), 256, 0, stream>>>(ff_w2, w2t, 1024, 512);
    transpose_cvt<<<dim3(256 / 32, 512 / 32), 256, 0, stream>>>(sem_w, semt, 512, 256);
    transpose_cvt<<<dim3(256 / 32, 512 / 32), 256, 0, stream>>>(epi_w, epit, 512, 256);

    // encoder, chunked over rows to bound workspace
    for (int cc = 0; cc < ML / RCH; ++cc) {
        int c0 = cc * RCH;
        gemm_ffn1<<<dim3(1024 / 128, RCH / 128), 256, 0, stream>>>(
            seq + c0, embed, w1t, ff_b1, t1c, 1024, 512);
        gemm_ffn2<<<dim3(512 / 128, RCH / 128), 256, 0, stream>>>(
            t1c, w2t, ff_b2, seq + c0, embed, ebc, 512, 1024);
        ln_kernel<<<RCH / 4, 256, 0, stream>>>(ebc, ln_g, ln_b);  // h, in-place
        gemm_proj<<<dim3(512 / 128, RCH / 128), 256, 0, stream>>>(
            ebc, semt, sem_b, epi_b,
            ks_bf + (size_t)c0 * HALFD, ke_bf + (size_t)c0 * HALFD, 512);
    }

    beta_kernel<<<ML / 4, 256, 0, stream>>>(ks_bf, bet_s);
    beta_kernel<<<ML / 4, 256, 0, stream>>>(ke_bf, bet_e);

    tinv_kernel<<<512, 256, 0, stream>>>(ks_bf, ke_bf, bet_s, bet_e, Dbuf);
    scan_kernel<<<256, 512, 0, stream>>>(ks_bf, ke_bf, bet_s, bet_e, Dbuf, cbuf);

    out_gemm<<<dim3(125, 4), 512, 0, stream>>>(cbuf, out_w, out_b, outp);
}

// Round 6
// 927.495 us; speedup vs baseline: 1.3959x; 1.3959x over previous
//
#include <hip/hip_runtime.h>

typedef unsigned short ushort_t;
typedef unsigned int uint_t;
typedef __attribute__((ext_vector_type(8))) short short8;
typedef __attribute__((ext_vector_type(4))) float f32x4;

static constexpr int V = 32000, H = 512, HALFD = 256, LSEQ = 1024, BB = 64;

__device__ __forceinline__ ushort_t f2bf(float f) {
    uint_t u = __float_as_uint(f);
    u = (u + 0x7FFFu + ((u >> 16) & 1u)) >> 16;
    return (ushort_t)u;
}
__device__ __forceinline__ float bf2f(ushort_t u) {
    return __uint_as_float(((uint_t)u) << 16);
}
__device__ __forceinline__ float bflo(uint_t u) { return __uint_as_float(u << 16); }
__device__ __forceinline__ float bfhi(uint_t u) { return __uint_as_float(u & 0xffff0000u); }
__device__ __forceinline__ float bfres(float v) { return v - bf2f(f2bf(v)); }

// ---- async global->LDS (width 16); dest = wave-uniform base + lane*16 ------------
typedef const __attribute__((address_space(1))) void* gas_ptr;
typedef __attribute__((address_space(3))) void* las_ptr;
#define GLDS16(g, l) __builtin_amdgcn_global_load_lds((gas_ptr)(g), (las_ptr)(l), 16, 0, 0)

// ---- encoder LDS addressing: packed 64B rows (4x16B chunks), XOR-swizzled --------
// slot(row, chunk) = chunk ^ ((row>>1)&3).  Conflict-free for lid-row frag reads
// AND linear (byte = t*16) for global_load_lds staging with pre-swizzled source.
__device__ __forceinline__ const short8* rd64(const ushort_t* b, int row, int chunk) {
    return (const short8*)(b + row * 32 + (((chunk ^ ((row >> 1) & 3)) & 3) << 3));
}
__device__ __forceinline__ ushort_t* wr64(ushort_t* b, int row, int chunk) {
    return b + row * 32 + (((chunk ^ ((row >> 1) & 3)) & 3) << 3);
}

// ---------------- weight transpose + fp32->bf16 convert: Wt[n][k] = bf16(W[k][n]) --
__global__ void transpose_cvt(const float* __restrict__ W, ushort_t* __restrict__ Wt,
                              int K, int N) {
    __shared__ float tile[32][33];
    int k0 = blockIdx.y * 32, n0 = blockIdx.x * 32;
    int tx = threadIdx.x & 31, ty = threadIdx.x >> 5;   // 256 threads: ty 0..7
    #pragma unroll
    for (int i = 0; i < 32; i += 8)
        tile[ty + i][tx] = W[(size_t)(k0 + ty + i) * N + n0 + tx];
    __syncthreads();
    #pragma unroll
    for (int i = 0; i < 32; i += 8)
        Wt[(size_t)(n0 + ty + i) * K + k0 + tx] = f2bf(tile[tx][ty + i]);
}

// ======================= GEMM 1: t1 = relu(gather(embed,seq) @ w1 + b1) ===========
// 64x128 tile (waves 2x2, each 32x64, acc[2][4]) -> grid (8, RCH/64): 2x the blocks
// of the 128-tile version (encoder was occupancy-starved at 1-2 blocks/CU).
__global__ __launch_bounds__(256) void gemm_ffn1(
        const int* __restrict__ seqp, const float* __restrict__ embed,
        const ushort_t* __restrict__ Bt, const float* __restrict__ bias,
        ushort_t* __restrict__ Cout, int N, int K) {
    __shared__ __align__(16) ushort_t Al[2048];         // 64 rows x 64B (swz)
    __shared__ __align__(16) ushort_t Bl[4096];         // 128 rows x 64B
    int t = threadIdx.x;
    int m0 = blockIdx.y * 64, n0 = blockIdx.x * 128;
    int lane = t & 63, wid = t >> 6;
    int wm = (wid & 1) * 32, wn = (wid >> 1) * 64;
    int lid = lane & 15, quad = lane >> 4;
    int srow = t >> 2;                                  // staging row 0..63
    int gch = (t & 3) ^ ((t >> 3) & 3);                 // pre-swizzled global chunk

    int tok0 = seqp[m0 + srow];
    const float* e0 = embed + (size_t)tok0 * H + (t & 3) * 8;
    const ushort_t* b0p = Bt + (size_t)(n0 + srow) * K + gch * 8;
    const ushort_t* b1p = Bt + (size_t)(n0 + 64 + srow) * K + gch * 8;
    ushort_t* ldsB = Bl + wid * 512;                    // wave-uniform base
    ushort_t* aw0 = wr64(Al, srow, t & 3);

    f32x4 acc[2][4];
    #pragma unroll
    for (int i = 0; i < 2; ++i)
        #pragma unroll
        for (int j = 0; j < 4; ++j)
            acc[i][j] = (f32x4){0.f, 0.f, 0.f, 0.f};

    for (int k0 = 0; k0 < K; k0 += 32) {
        __syncthreads();                                // prior frag reads done
        GLDS16(b0p + k0, ldsB);
        GLDS16(b1p + k0, ldsB + 2048);
        float4 ea0 = *(const float4*)(e0 + k0);
        float4 eb0 = *(const float4*)(e0 + k0 + 4);
        short8 s0;
        s0[0] = (short)f2bf(ea0.x); s0[1] = (short)f2bf(ea0.y);
        s0[2] = (short)f2bf(ea0.z); s0[3] = (short)f2bf(ea0.w);
        s0[4] = (short)f2bf(eb0.x); s0[5] = (short)f2bf(eb0.y);
        s0[6] = (short)f2bf(eb0.z); s0[7] = (short)f2bf(eb0.w);
        *(short8*)aw0 = s0;
        __syncthreads();                                // drains vmcnt + lds writes
        short8 af[2], bfr[4];
        #pragma unroll
        for (int i = 0; i < 2; ++i) af[i] = *rd64(Al, wm + i * 16 + lid, quad);
        #pragma unroll
        for (int i = 0; i < 4; ++i) bfr[i] = *rd64(Bl, wn + i * 16 + lid, quad);
        #pragma unroll
        for (int mt = 0; mt < 2; ++mt)
            #pragma unroll
            for (int nt = 0; nt < 4; ++nt)
                acc[mt][nt] = __builtin_amdgcn_mfma_f32_16x16x32_bf16(
                    af[mt], bfr[nt], acc[mt][nt], 0, 0, 0);
    }
    #pragma unroll
    for (int mt = 0; mt < 2; ++mt)
        #pragma unroll
        for (int nt = 0; nt < 4; ++nt)
            #pragma unroll
            for (int rg = 0; rg < 4; ++rg) {
                int row = m0 + wm + mt * 16 + quad * 4 + rg;
                int col = n0 + wn + nt * 16 + lid;
                float v = fmaxf(acc[mt][nt][rg] + bias[col], 0.f);
                Cout[(size_t)row * N + col] = f2bf(v);
            }
}

// ======================= GEMM 2: x = t1 @ w2 + b2 + gather(embed,seq) =============
__global__ __launch_bounds__(256) void gemm_ffn2(
        const ushort_t* __restrict__ A, const ushort_t* __restrict__ Bt,
        const float* __restrict__ bias, const int* __restrict__ seqp,
        const float* __restrict__ embed, ushort_t* __restrict__ Cout,
        int N, int K) {
    __shared__ __align__(16) ushort_t Al[2048];
    __shared__ __align__(16) ushort_t Bl[4096];
    int t = threadIdx.x;
    int m0 = blockIdx.y * 64, n0 = blockIdx.x * 128;
    int lane = t & 63, wid = t >> 6;
    int wm = (wid & 1) * 32, wn = (wid >> 1) * 64;
    int lid = lane & 15, quad = lane >> 4;
    int srow = t >> 2;
    int gch = (t & 3) ^ ((t >> 3) & 3);

    const ushort_t* a0p = A + (size_t)(m0 + srow) * K + gch * 8;
    const ushort_t* b0p = Bt + (size_t)(n0 + srow) * K + gch * 8;
    const ushort_t* b1p = Bt + (size_t)(n0 + 64 + srow) * K + gch * 8;
    ushort_t* ldsA = Al + wid * 512;
    ushort_t* ldsB = Bl + wid * 512;

    f32x4 acc[2][4];
    #pragma unroll
    for (int i = 0; i < 2; ++i)
        #pragma unroll
        for (int j = 0; j < 4; ++j)
            acc[i][j] = (f32x4){0.f, 0.f, 0.f, 0.f};

    for (int k0 = 0; k0 < K; k0 += 32) {
        __syncthreads();
        GLDS16(a0p + k0, ldsA);
        GLDS16(b0p + k0, ldsB);
        GLDS16(b1p + k0, ldsB + 2048);
        __syncthreads();
        short8 af[2], bfr[4];
        #pragma unroll
        for (int i = 0; i < 2; ++i) af[i] = *rd64(Al, wm + i * 16 + lid, quad);
        #pragma unroll
        for (int i = 0; i < 4; ++i) bfr[i] = *rd64(Bl, wn + i * 16 + lid, quad);
        #pragma unroll
        for (int mt = 0; mt < 2; ++mt)
            #pragma unroll
            for (int nt = 0; nt < 4; ++nt)
                acc[mt][nt] = __builtin_amdgcn_mfma_f32_16x16x32_bf16(
                    af[mt], bfr[nt], acc[mt][nt], 0, 0, 0);
    }
    #pragma unroll
    for (int mt = 0; mt < 2; ++mt)
        #pragma unroll
        for (int rg = 0; rg < 4; ++rg) {
            int row = m0 + wm + mt * 16 + quad * 4 + rg;
            int tok = seqp[row];
            const float* erow = embed + (size_t)tok * H;
            #pragma unroll
            for (int nt = 0; nt < 4; ++nt) {
                int col = n0 + wn + nt * 16 + lid;
                float v = acc[mt][nt][rg] + bias[col] + erow[col];
                Cout[(size_t)row * N + col] = f2bf(v);
            }
        }
}

// ====== fused projections: [ks|ke] = h @ [sem_w|epi_w] + b  (Bt rows concat) ======
__global__ __launch_bounds__(256) void gemm_proj(
        const ushort_t* __restrict__ A, const ushort_t* __restrict__ Bt,
        const float* __restrict__ biasS, const float* __restrict__ biasE,
        ushort_t* __restrict__ outS, ushort_t* __restrict__ outE, int K) {
    __shared__ __align__(16) ushort_t Al[2048];
    __shared__ __align__(16) ushort_t Bl[4096];
    int t = threadIdx.x;
    int m0 = blockIdx.y * 64, n0 = blockIdx.x * 128;    // n0 in 0..384
    int lane = t & 63, wid = t >> 6;
    int wm = (wid & 1) * 32, wn = (wid >> 1) * 64;
    int lid = lane & 15, quad = lane >> 4;
    int srow = t >> 2;
    int gch = (t & 3) ^ ((t >> 3) & 3);

    const ushort_t* a0p = A + (size_t)(m0 + srow) * K + gch * 8;
    const ushort_t* b0p = Bt + (size_t)(n0 + srow) * K + gch * 8;
    const ushort_t* b1p = Bt + (size_t)(n0 + 64 + srow) * K + gch * 8;
    ushort_t* ldsA = Al + wid * 512;
    ushort_t* ldsB = Bl + wid * 512;

    f32x4 acc[2][4];
    #pragma unroll
    for (int i = 0; i < 2; ++i)
        #pragma unroll
        for (int j = 0; j < 4; ++j)
            acc[i][j] = (f32x4){0.f, 0.f, 0.f, 0.f};

    for (int k0 = 0; k0 < K; k0 += 32) {
        __syncthreads();
        GLDS16(a0p + k0, ldsA);
        GLDS16(b0p + k0, ldsB);
        GLDS16(b1p + k0, ldsB + 2048);
        __syncthreads();
        short8 af[2], bfr[4];
        #pragma unroll
        for (int i = 0; i < 2; ++i) af[i] = *rd64(Al, wm + i * 16 + lid, quad);
        #pragma unroll
        for (int i = 0; i < 4; ++i) bfr[i] = *rd64(Bl, wn + i * 16 + lid, quad);
        #pragma unroll
        for (int mt = 0; mt < 2; ++mt)
            #pragma unroll
            for (int nt = 0; nt < 4; ++nt)
                acc[mt][nt] = __builtin_amdgcn_mfma_f32_16x16x32_bf16(
                    af[mt], bfr[nt], acc[mt][nt], 0, 0, 0);
    }
    #pragma unroll
    for (int mt = 0; mt < 2; ++mt)
        #pragma unroll
        for (int nt = 0; nt < 4; ++nt)
            #pragma unroll
            for (int rg = 0; rg < 4; ++rg) {
                int row = m0 + wm + mt * 16 + quad * 4 + rg;
                int col = n0 + wn + nt * 16 + lid;   // wave-uniform half selection
                if (col < 256)
                    outS[(size_t)row * HALFD + col] = f2bf(acc[mt][nt][rg] + biasS[col]);
                else
                    outE[(size_t)row * HALFD + col - 256] =
                        f2bf(acc[mt][nt][rg] + biasE[col - 256]);
            }
}

// ---------------- LayerNorm over H=512 (bf16 in-place), one wave per row ----------
__global__ void ln_kernel(ushort_t* X, const float* __restrict__ g,
                          const float* __restrict__ bta) {
    int row = blockIdx.x * 4 + (threadIdx.x >> 6);
    int lane = threadIdx.x & 63;
    ushort_t* xr = X + (size_t)row * H + lane * 8;
    short8 xv = *(short8*)xr;
    float x[8];
    #pragma unroll
    for (int j = 0; j < 8; ++j) x[j] = bf2f((ushort_t)xv[j]);
    float s = 0.f, ss = 0.f;
    #pragma unroll
    for (int j = 0; j < 8; ++j) { s += x[j]; ss += x[j] * x[j]; }
    #pragma unroll
    for (int d = 1; d < 64; d <<= 1) { s += __shfl_xor(s, d); ss += __shfl_xor(ss, d); }
    float mu = s * (1.f / 512.f);
    float var = ss * (1.f / 512.f) - mu * mu;
    float rstd = rsqrtf(var + 1e-5f);
    float4 g0 = *(const float4*)(g + lane * 8);
    float4 g1 = *(const float4*)(g + lane * 8 + 4);
    float4 b0 = *(const float4*)(bta + lane * 8);
    float4 b1 = *(const float4*)(bta + lane * 8 + 4);
    float gg[8] = {g0.x, g0.y, g0.z, g0.w, g1.x, g1.y, g1.z, g1.w};
    float bb[8] = {b0.x, b0.y, b0.z, b0.w, b1.x, b1.y, b1.z, b1.w};
    short8 o;
    #pragma unroll
    for (int j = 0; j < 8; ++j)
        o[j] = (short)f2bf((x[j] - mu) * rstd * gg[j] + bb[j]);
    *(short8*)xr = o;
}

// ---------------- beta[row] = sum(k^2) + 1e-6 (bf16 input), one wave per row ------
__global__ void beta_kernel(const ushort_t* __restrict__ k, float* __restrict__ beta) {
    int row = blockIdx.x * 4 + (threadIdx.x >> 6);
    int lane = threadIdx.x & 63;
    ushort4 a = *(const ushort4*)(k + (size_t)row * HALFD + lane * 4);
    float ax = bf2f(a.x), ay = bf2f(a.y), az = bf2f(a.z), aw = bf2f(a.w);
    float s = ax * ax + ay * ay + az * az + aw * aw;
    #pragma unroll
    for (int d = 1; d < 64; d <<= 1) s += __shfl_xor(s, d);
    if (lane == 0) beta[row] = s + 1e-6f;
}

// ================= chunked delta-rule: Tinv precompute (barrier-free fsub) ========
__global__ __launch_bounds__(256) void tinv_kernel(
        const ushort_t* __restrict__ ks, const ushort_t* __restrict__ ke,
        const float* __restrict__ beta_s, const float* __restrict__ beta_e,
        ushort_t* __restrict__ Dg) {
    __shared__ __align__(16) ushort_t Kl[64][280];
    __shared__ __align__(16) ushort_t LmT[4][64][66];   // LmT[pp][j][i] = L[i][j]
    __shared__ float betsl[4][64];

    int t = threadIdx.x;
    int lane = t & 63, wv = t >> 6;
    int lid = lane & 15, quad = lane >> 4;
    int blk0 = blockIdx.x * 4;
    const float invL = 1.0f / 1024.0f;

    for (int pp = 0; pp < 4; ++pp) {
        int p = blk0 + pp;
        int ch = p & 15, bm = p >> 4;
        int mat = bm & 1, b = bm >> 1;
        const ushort_t* Kp = (mat ? ke : ks) + ((size_t)b * LSEQ + ch * 64) * HALFD;
        const float* Bp = (mat ? beta_e : beta_s) + (size_t)b * LSEQ + ch * 64;

        __syncthreads();                    // Kl free (prev pp's MFMA reads done)
        {   // stage K chunk (64 x 256 bf16)
            int j = t >> 2, c0 = (t & 3) * 64;
            const ushort_t* src = Kp + (size_t)j * HALFD + c0;
            #pragma unroll
            for (int x = 0; x < 8; ++x)
                *(short8*)&Kl[j][c0 + x * 8] = *(const short8*)(src + x * 8);
        }
        if (t < 64) betsl[pp][t] = Bp[t];
        __syncthreads();

        // G = K K^T; wave wv owns rows wv*16..+16
        f32x4 g[4];
        #pragma unroll
        for (int i = 0; i < 4; ++i) g[i] = (f32x4){0.f, 0.f, 0.f, 0.f};
        #pragma unroll
        for (int kc = 0; kc < 8; ++kc) {
            short8 af = *(const short8*)&Kl[wv * 16 + lid][kc * 32 + quad * 8];
            #pragma unroll
            for (int nt = 0; nt < 4; ++nt) {
                short8 bq = *(const short8*)&Kl[nt * 16 + lid][kc * 32 + quad * 8];
                g[nt] = __builtin_amdgcn_mfma_f32_16x16x32_bf16(af, bq, g[nt], 0, 0, 0);
            }
        }
        #pragma unroll
        for (int nt = 0; nt < 4; ++nt)
            #pragma unroll
            for (int rg = 0; rg < 4; ++rg) {
                int i = wv * 16 + quad * 4 + rg;     // row of L
                int j = nt * 16 + lid;               // col of L
                int s = ch * 64 + i;
                float wgt = mat ? (float)(s + 1) * invL : 1.0f;
                if (s >= 1023) wgt = 0.f;            // padding step
                float wb = wgt / betsl[pp][i];
                LmT[pp][j][i] = f2bf((j < i) ? g[nt][rg] * wb : 0.f);
            }
    }
    __syncthreads();                        // all LmT ready

    // barrier-free fsub: wave wv owns problem blk0+wv; lane owns column `lane`
    const ushort_t (*Lp)[66] = LmT[wv];
    float a[64];
    #pragma unroll
    for (int x = 0; x < 32; ++x) {          // a[i] = -L[i][lane] = -LmT[lane][i]
        uint_t u = *(const uint_t*)&Lp[lane][x * 2];
        a[x * 2]     = -bflo(u);
        a[x * 2 + 1] = -bfhi(u);
    }
    #pragma unroll
    for (int j = 0; j < 63; ++j) {
        float dj = a[j];
        const ushort_t* rowj = Lp[j];
        #pragma unroll
        for (int ii = (j + 1) & ~1; ii < 64; ii += 2) {
            uint_t u = *(const uint_t*)&rowj[ii];    // wave-uniform broadcast
            if (ii > j) a[ii] -= bflo(u) * dj;
            a[ii + 1]        -= bfhi(u) * dj;
        }
    }
    size_t pbase = (size_t)(blk0 + wv) * 4096;
    #pragma unroll
    for (int i = 0; i < 64; ++i)
        Dg[pbase + (size_t)i * 64 + lane] = f2bf(a[i]);
}

// ================= chunked delta-rule scan (MFMA) — r3 version (proven 147 us) ====
// r5's swizzled variant spilled to scratch (WRITE_SIZE 128KB->246MB, VGPR 128):
// reverted verbatim. The 16.5M bank-conflict cycles cost <= ~27 us — acceptable.
__global__ __launch_bounds__(512) void scan_kernel(
        const ushort_t* __restrict__ ks, const ushort_t* __restrict__ ke,
        const float* __restrict__ beta_s, const float* __restrict__ beta_e,
        const ushort_t* __restrict__ Dg, float* __restrict__ c) {
    int blk = blockIdx.x;
    int b = blk >> 2, mat = (blk >> 1) & 1, half = blk & 1;
    const ushort_t* Kp = (mat ? ke : ks) + (size_t)b * LSEQ * HALFD;
    const float* Bp = (mat ? beta_e : beta_s) + (size_t)b * LSEQ;
    const ushort_t* Dp = Dg + (size_t)(b * 2 + mat) * 16 * 4096;

    __shared__ __align__(16) ushort_t Kl[64][264];      // K chunk [j][c]
    __shared__ __align__(16) ushort_t MK[33792];        // union: Ml[128][264] | Kt[256][72]
    __shared__ __align__(16) ushort_t RHSl[128][72];    // RHS^T [r][j']
    __shared__ __align__(16) ushort_t Ul[128][72];      // U^T [r][j]
    __shared__ __align__(16) ushort_t Dl[64][72];       // Tinv - I [j][j']
    __shared__ float bets[LSEQ];

    ushort_t (*Ml)[264] = (ushort_t(*)[264])MK;
    ushort_t (*Kt)[72]  = (ushort_t(*)[72])MK;

    int t = threadIdx.x;
    int lane = t & 63, wid = t >> 6;
    int lid = lane & 15, quad = lane >> 4;
    int wm  = (wid & 1) * 64, wn  = (wid >> 1) * 64;    // GEMM3/M org: 128x256 tile
    int wm1 = (wid & 1) * 64, wn1 = (wid >> 1) * 16;    // GEMM1/2 org: 128x64 tile

    #pragma unroll
    for (int i = 0; i < 2; ++i) bets[t + i * 512] = Bp[t + i * 512];

    f32x4 acc[4][4];
    #pragma unroll
    for (int i = 0; i < 4; ++i)
        #pragma unroll
        for (int j = 0; j < 4; ++j)
            acc[i][j] = (f32x4){0.f, 0.f, 0.f, 0.f};

    // K staging: thread t -> row sj, 4 x short8 at cols (t&7)*8 + x*64 (coalesced)
    int sj = t >> 3, scb = (t & 7) * 8;
    short8 pf[4];
    {
        const ushort_t* kr = Kp + (size_t)sj * HALFD + scb;
        #pragma unroll
        for (int x = 0; x < 4; ++x) pf[x] = *(const short8*)(kr + x * 64);
    }
    short8 dpf = *(const short8*)(Dp + t * 8);
    const float invL = 1.0f / 1024.0f;

    for (int ch = 0; ch < 16; ++ch) {
        __syncthreads();                       // F: prior-chunk LDS reads done
        #pragma unroll
        for (int x = 0; x < 4; ++x) *(short8*)&Kl[sj][scb + x * 64] = pf[x];
        *(short8*)&Dl[t >> 3][(t & 7) * 8] = dpf;
        // M_hi -> Ml
        #pragma unroll
        for (int mt = 0; mt < 4; ++mt)
            #pragma unroll
            for (int nt = 0; nt < 4; ++nt)
                #pragma unroll
                for (int rg = 0; rg < 4; ++rg)
                    Ml[wm + mt * 16 + quad * 4 + rg][wn + nt * 16 + lid] =
                        f2bf(acc[mt][nt][rg]);
        // prefetch next chunk
        int nch = (ch + 1 < 16) ? ch + 1 : 15;
        {
            const ushort_t* kr = Kp + ((size_t)nch * 64 + sj) * HALFD + scb;
            #pragma unroll
            for (int x = 0; x < 4; ++x) pf[x] = *(const short8*)(kr + x * 64);
            dpf = *(const short8*)(Dp + (size_t)nch * 4096 + t * 8);
        }
        __syncthreads();                       // A

        // GEMM1 hi: P0^T[r,i] += sum_c Mhi[r,c] K[i,c]
        f32x4 p0[4];
        #pragma unroll
        for (int i = 0; i < 4; ++i) p0[i] = (f32x4){0.f, 0.f, 0.f, 0.f};
        #pragma unroll
        for (int kc = 0; kc < 8; ++kc) {
            short8 bq = *(const short8*)&Kl[wn1 + lid][kc * 32 + quad * 8];
            #pragma unroll
            for (int mt = 0; mt < 4; ++mt) {
                short8 aq = *(const short8*)&Ml[wm1 + mt * 16 + lid][kc * 32 + quad * 8];
                p0[mt] = __builtin_amdgcn_mfma_f32_16x16x32_bf16(aq, bq, p0[mt], 0, 0, 0);
            }
        }
        __syncthreads();                       // B: Ml(hi) reads done
        // M_lo -> Ml
        #pragma unroll
        for (int mt = 0; mt < 4; ++mt)
            #pragma unroll
            for (int nt = 0; nt < 4; ++nt)
                #pragma unroll
                for (int rg = 0; rg < 4; ++rg) {
                    float v = acc[mt][nt][rg];
                    Ml[wm + mt * 16 + quad * 4 + rg][wn + nt * 16 + lid] =
                        f2bf(v - bf2f(f2bf(v)));
                }
        __syncthreads();                       // C
        // GEMM1 lo
        #pragma unroll
        for (int kc = 0; kc < 8; ++kc) {
            short8 bq = *(const short8*)&Kl[wn1 + lid][kc * 32 + quad * 8];
            #pragma unroll
            for (int mt = 0; mt < 4; ++mt) {
                short8 aq = *(const short8*)&Ml[wm1 + mt * 16 + lid][kc * 32 + quad * 8];
                p0[mt] = __builtin_amdgcn_mfma_f32_16x16x32_bf16(aq, bq, p0[mt], 0, 0, 0);
            }
        }
        // RHS: rhs[r,i] = w_i*k_i[hr] - (w_i/beta_i)*P0^T[r,i]
        int iB = wn1 + lid;
        int s = ch * 64 + iB;
        float wgt = mat ? (float)(s + 1) * invL : 1.0f;
        if (s >= 1023) wgt = 0.f;
        float wb = wgt / bets[s];
        float rhsf[4][4];
        #pragma unroll
        for (int mt = 0; mt < 4; ++mt)
            #pragma unroll
            for (int rg = 0; rg < 4; ++rg) {
                int r = wm1 + mt * 16 + quad * 4 + rg;
                float kv = bf2f(Kl[iB][half * 128 + r]);
                float rv = wgt * kv - wb * p0[mt][rg];
                rhsf[mt][rg] = rv;
                RHSl[r][iB] = f2bf(rv);
            }
        __syncthreads();                       // D: RHS ready; Ml region free

        // build Kt[c][j] = K[j][c] into the (free) Ml region
        {
            int c0 = wid * 32;
            #pragma unroll
            for (int rr = 0; rr < 4; ++rr) {
                short8 kv8 = *(const short8*)&Kl[lane][c0 + rr * 8];
                #pragma unroll
                for (int x = 0; x < 8; ++x)
                    Kt[c0 + rr * 8 + x][lane] = (ushort_t)kv8[x];
            }
        }
        // GEMM2: corr[r,j] = sum_j' RHS^T[r,j'] * D[j,j']
        f32x4 uf[4];
        #pragma unroll
        for (int i = 0; i < 4; ++i) uf[i] = (f32x4){0.f, 0.f, 0.f, 0.f};
        #pragma unroll
        for (int kc = 0; kc < 2; ++kc) {
            short8 bq = *(const short8*)&Dl[wn1 + lid][kc * 32 + quad * 8];
            #pragma unroll
            for (int mt = 0; mt < 4; ++mt) {
                short8 aq = *(const short8*)&RHSl[wm1 + mt * 16 + lid][kc * 32 + quad * 8];
                uf[mt] = __builtin_amdgcn_mfma_f32_16x16x32_bf16(aq, bq, uf[mt], 0, 0, 0);
            }
        }
        // u = corr + RHS (exact fp32 RHS from regs; frag positions identical)
        #pragma unroll
        for (int mt = 0; mt < 4; ++mt)
            #pragma unroll
            for (int rg = 0; rg < 4; ++rg) {
                int r = wm1 + mt * 16 + quad * 4 + rg;
                Ul[r][wn1 + lid] = f2bf(uf[mt][rg] + rhsf[mt][rg]);
            }
        __syncthreads();                       // E: Kt + U(hi) ready
        // GEMM3 hi: M += Uhi^T * K
        #pragma unroll
        for (int kc = 0; kc < 2; ++kc) {
            short8 bq4[4];
            #pragma unroll
            for (int nt = 0; nt < 4; ++nt)
                bq4[nt] = *(const short8*)&Kt[wn + nt * 16 + lid][kc * 32 + quad * 8];
            #pragma unroll
            for (int mt = 0; mt < 4; ++mt) {
                short8 aq = *(const short8*)&Ul[wm + mt * 16 + lid][kc * 32 + quad * 8];
                #pragma unroll
                for (int nt = 0; nt < 4; ++nt)
                    acc[mt][nt] = __builtin_amdgcn_mfma_f32_16x16x32_bf16(
                        aq, bq4[nt], acc[mt][nt], 0, 0, 0);
            }
        }
        __syncthreads();                       // E2: Ul(hi) reads done
        #pragma unroll
        for (int mt = 0; mt < 4; ++mt)
            #pragma unroll
            for (int rg = 0; rg < 4; ++rg) {
                int r = wm1 + mt * 16 + quad * 4 + rg;
                float u = uf[mt][rg] + rhsf[mt][rg];
                Ul[r][wn1 + lid] = f2bf(u - bf2f(f2bf(u)));
            }
        __syncthreads();                       // E3
        // GEMM3 lo
        #pragma unroll
        for (int kc = 0; kc < 2; ++kc) {
            short8 bq4[4];
            #pragma unroll
            for (int nt = 0; nt < 4; ++nt)
                bq4[nt] = *(const short8*)&Kt[wn + nt * 16 + lid][kc * 32 + quad * 8];
            #pragma unroll
            for (int mt = 0; mt < 4; ++mt) {
                short8 aq = *(const short8*)&Ul[wm + mt * 16 + lid][kc * 32 + quad * 8];
                #pragma unroll
                for (int nt = 0; nt < 4; ++nt)
                    acc[mt][nt] = __builtin_amdgcn_mfma_f32_16x16x32_bf16(
                        aq, bq4[nt], acc[mt][nt], 0, 0, 0);
            }
        }
    }

    // final matvec: c[hr] = sum_c M[hr,c] * k[1023][c]  (k[1023] = Kl row 63)
    __syncthreads();
    float* vsc = (float*)RHSl;                 // 4 x 128 scratch
    float kvv[4];
    #pragma unroll
    for (int nt = 0; nt < 4; ++nt)
        kvv[nt] = bf2f(Kl[63][wn + nt * 16 + lid]);
    #pragma unroll
    for (int mt = 0; mt < 4; ++mt)
        #pragma unroll
        for (int rg = 0; rg < 4; ++rg) {
            float p = acc[mt][0][rg] * kvv[0] + acc[mt][1][rg] * kvv[1]
                    + acc[mt][2][rg] * kvv[2] + acc[mt][3][rg] * kvv[3];
            p += __shfl_xor(p, 1); p += __shfl_xor(p, 2);
            p += __shfl_xor(p, 4); p += __shfl_xor(p, 8);
            if (lid == 0)
                vsc[(wid >> 1) * 128 + wm + mt * 16 + quad * 4 + rg] = p;
        }
    __syncthreads();
    if (t < 128) {
        float sum = vsc[t] + vsc[128 + t] + vsc[256 + t] + vsc[384 + t];
        c[(size_t)b * 512 + mat * 256 + half * 128 + t] = sum;
    }
}

// ---------------- output GEMM: out[64x32000] = c[64x512] @ W[512x32000] + b -------
__global__ __launch_bounds__(512) void out_gemm(
        const float* __restrict__ c, const float* __restrict__ W,
        const float* __restrict__ bias, float* __restrict__ out) {
    __shared__ __align__(16) float cl[16][512];
    int t = threadIdx.x;
    int lane = t & 63, w = t >> 6;                    // 8 waves
    int cb = blockIdx.x * 256;                        // 125*256 = 32000
    int rb = blockIdx.y * 16;                         // 4*16 = 64 rows

    #pragma unroll
    for (int i = 0; i < 4; ++i) {
        int idx = t + i * 512;                        // float4 index
        int row = idx >> 7, c4 = (idx & 127) * 4;
        *(float4*)&cl[row][c4] = *(const float4*)(c + (size_t)(rb + row) * 512 + c4);
    }
    __syncthreads();

    const float* wp = W + cb + lane * 4;
    int r0 = w * 2;
    f32x4 a0 = (f32x4){0.f, 0.f, 0.f, 0.f};
    f32x4 a1 = (f32x4){0.f, 0.f, 0.f, 0.f};

    #pragma unroll 2
    for (int k = 0; k < 512; k += 4) {
        f32x4 w0 = *(const f32x4*)(wp + (size_t)(k + 0) * V);
        f32x4 w1 = *(const f32x4*)(wp + (size_t)(k + 1) * V);
        f32x4 w2 = *(const f32x4*)(wp + (size_t)(k + 2) * V);
        f32x4 w3 = *(const f32x4*)(wp + (size_t)(k + 3) * V);
        f32x4 ca = *(const f32x4*)&cl[r0][k];
        f32x4 cb4 = *(const f32x4*)&cl[r0 + 1][k];
        a0 += ca[0] * w0; a0 += ca[1] * w1; a0 += ca[2] * w2; a0 += ca[3] * w3;
        a1 += cb4[0] * w0; a1 += cb4[1] * w1; a1 += cb4[2] * w2; a1 += cb4[3] * w3;
    }
    f32x4 bv = *(const f32x4*)(bias + cb + lane * 4);
    *(f32x4*)(out + (size_t)(rb + r0) * V + cb + lane * 4) = a0 + bv;
    *(f32x4*)(out + (size_t)(rb + r0 + 1) * V + cb + lane * 4) = a1 + bv;
}

// ---------------- launch ----------------------------------------------------------
extern "C" void kernel_launch(void* const* d_in, const int* in_sizes, int n_in,
                              void* d_out, int out_size, void* d_ws, size_t ws_size,
                              hipStream_t stream) {
    const int*   seq    = (const int*)d_in[0];
    const float* embed  = (const float*)d_in[1];
    const float* ff_w1  = (const float*)d_in[2];
    const float* ff_b1  = (const float*)d_in[3];
    const float* ff_w2  = (const float*)d_in[4];
    const float* ff_b2  = (const float*)d_in[5];
    const float* ln_g   = (const float*)d_in[6];
    const float* ln_b   = (const float*)d_in[7];
    const float* sem_w  = (const float*)d_in[8];
    const float* sem_b  = (const float*)d_in[9];
    const float* epi_w  = (const float*)d_in[10];
    const float* epi_b  = (const float*)d_in[11];
    const float* out_w  = (const float*)d_in[12];
    const float* out_b  = (const float*)d_in[13];
    float* outp = (float*)d_out;

    const int ML = BB * LSEQ;                         // 65536 rows
    int RCH;
    if      (ws_size >= 271712256ull) RCH = 65536;    // 1 chunk
    else if (ws_size >= 120717312ull) RCH = 16384;    // 4 chunks
    else                              RCH = 8192;     // 8 chunks (95,551,488 proven)

    char* w = (char*)d_ws;
    size_t off = 0;
    ushort_t* ks_bf = (ushort_t*)(w + off); off += 33554432;          // 65536x256 bf16
    ushort_t* ke_bf = (ushort_t*)(w + off); off += 33554432;
    ushort_t* ebc   = (ushort_t*)(w + off); off += (size_t)RCH * 512 * 2;   // x/h chunk
    ushort_t* t1c   = (ushort_t*)(w + off); off += (size_t)RCH * 1024 * 2;  // relu chunk
    ushort_t* w1t   = (ushort_t*)(w + off); off += 1048576;
    ushort_t* w2t   = (ushort_t*)(w + off); off += 1048576;
    ushort_t* semt  = (ushort_t*)(w + off); off += 262144;            // semt|epit adjacent
    ushort_t* epit  = (ushort_t*)(w + off); off += 262144;
    float*    bet_s = (float*)(w + off);    off += 262144;
    float*    bet_e = (float*)(w + off);    off += 262144;
    float*    cbuf  = (float*)(w + off);    off += 131072;
    // Tinv-I storage (2048 x 64 x 64 bf16 = 16.8 MB) reuses encoder chunk region.
    ushort_t* Dbuf  = ebc;
    (void)t1c;

    // weight prep (bf16 + transpose)
    transpose_cvt<<<dim3(1024 / 32, 512 / 32), 256, 0, stream>>>(ff_w1, w1t, 512, 1024);
    transpose_cvt<<<dim3(512 / 32, 1024 / 32), 256, 0, stream>>>(ff_w2, w2t, 1024, 512);
    transpose_cvt<<<dim3(256 / 32, 512 / 32), 256, 0, stream>>>(sem_w, semt, 512, 256);
    transpose_cvt<<<dim3(256 / 32, 512 / 32), 256, 0, stream>>>(epi_w, epit, 512, 256);

    // encoder, chunked over rows to bound workspace (64-row tiles -> 2-4 blocks/CU)
    for (int cc = 0; cc < ML / RCH; ++cc) {
        int c0 = cc * RCH;
        gemm_ffn1<<<dim3(1024 / 128, RCH / 64), 256, 0, stream>>>(
            seq + c0, embed, w1t, ff_b1, t1c, 1024, 512);
        gemm_ffn2<<<dim3(512 / 128, RCH / 64), 256, 0, stream>>>(
            t1c, w2t, ff_b2, seq + c0, embed, ebc, 512, 1024);
        ln_kernel<<<RCH / 4, 256, 0, stream>>>(ebc, ln_g, ln_b);  // h, in-place
        gemm_proj<<<dim3(512 / 128, RCH / 64), 256, 0, stream>>>(
            ebc, semt, sem_b, epi_b,
            ks_bf + (size_t)c0 * HALFD, ke_bf + (size_t)c0 * HALFD, 512);
    }

    beta_kernel<<<ML / 4, 256, 0, stream>>>(ks_bf, bet_s);
    beta_kernel<<<ML / 4, 256, 0, stream>>>(ke_bf, bet_e);

    tinv_kernel<<<512, 256, 0, stream>>>(ks_bf, ke_bf, bet_s, bet_e, Dbuf);
    scan_kernel<<<256, 512, 0, stream>>>(ks_bf, ke_bf, bet_s, bet_e, Dbuf, cbuf);

    out_gemm<<<dim3(125, 4), 512, 0, stream>>>(cbuf, out_w, out_b, outp);
}

// Round 7
// 921.975 us; speedup vs baseline: 1.4042x; 1.0060x over previous
//
#include <hip/hip_runtime.h>

typedef unsigned short ushort_t;
typedef unsigned int uint_t;
typedef __attribute__((ext_vector_type(8))) short short8;
typedef __attribute__((ext_vector_type(4))) float f32x4;

static constexpr int V = 32000, H = 512, HALFD = 256, LSEQ = 1024, BB = 64;

__device__ __forceinline__ ushort_t f2bf(float f) {
    uint_t u = __float_as_uint(f);
    u = (u + 0x7FFFu + ((u >> 16) & 1u)) >> 16;
    return (ushort_t)u;
}
__device__ __forceinline__ float bf2f(ushort_t u) {
    return __uint_as_float(((uint_t)u) << 16);
}
__device__ __forceinline__ float bflo(uint_t u) { return __uint_as_float(u << 16); }
__device__ __forceinline__ float bfhi(uint_t u) { return __uint_as_float(u & 0xffff0000u); }
__device__ __forceinline__ float bfres(float v) { return v - bf2f(f2bf(v)); }

// ---- async global->LDS (width 16); dest = wave-uniform base + lane*16 ------------
typedef const __attribute__((address_space(1))) void* gas_ptr;
typedef __attribute__((address_space(3))) void* las_ptr;
#define GLDS16(g, l) __builtin_amdgcn_global_load_lds((gas_ptr)(g), (las_ptr)(l), 16, 0, 0)

// Encoder LDS: BK=64 -> 128B rows (64 ushorts), 8 x 16B slots/row.
// slot(row, chunk) = chunk ^ (row & 7).
//  - ds_read_b128 frags: each aligned 8-lane group covers all 8 slots (lid&7 spans
//    0..7; tile row bases are multiples of 8) -> conflict-free.
//  - GLDS16 staging: dest linear (lane*16); source pre-swizzled with same involution.

// ---------------- weight transpose + fp32->bf16 convert: Wt[n][k] = bf16(W[k][n]) --
__global__ void transpose_cvt(const float* __restrict__ W, ushort_t* __restrict__ Wt,
                              int K, int N) {
    __shared__ float tile[32][33];
    int k0 = blockIdx.y * 32, n0 = blockIdx.x * 32;
    int tx = threadIdx.x & 31, ty = threadIdx.x >> 5;   // 256 threads: ty 0..7
    #pragma unroll
    for (int i = 0; i < 32; i += 8)
        tile[ty + i][tx] = W[(size_t)(k0 + ty + i) * N + n0 + tx];
    __syncthreads();
    #pragma unroll
    for (int i = 0; i < 32; i += 8)
        Wt[(size_t)(n0 + ty + i) * K + k0 + tx] = f2bf(tile[tx][ty + i]);
}

// ======================= GEMM 1: t1 = relu(gather(embed,seq) @ w1 + b1) ===========
// M=64 x N=128 tile, BK=64, double-buffered LDS, ONE barrier per K-step (T3-min
// 2-phase): STAGE(next buf) issued BEFORE compute so global latency hides under
// the ds_read+MFMA phase. B via global_load_lds; A = fp32 gather -> bf16 -> LDS.
__global__ __launch_bounds__(256) void gemm_ffn1(
        const int* __restrict__ seqp, const float* __restrict__ embed,
        const ushort_t* __restrict__ Bt, const float* __restrict__ bias,
        ushort_t* __restrict__ Cout, int N, int K) {
    __shared__ __align__(16) ushort_t Al[2][4096];      // 64 rows x 128B
    __shared__ __align__(16) ushort_t Bl[2][8192];      // 128 rows x 128B
    int t = threadIdx.x;
    int m0 = blockIdx.y * 64, n0 = blockIdx.x * 128;
    int lane = t & 63, wid = t >> 6;
    int wm = (wid & 1) * 32, wn = (wid >> 1) * 64;
    int lid = lane & 15, quad = lane >> 4;

    // B staging: j=0..3 -> row=(t>>3)+j*32, slot=t&7, source chunk pre-swizzled
    int gch = (t & 7) ^ ((t >> 3) & 7);
    const ushort_t* bp = Bt + (size_t)(n0 + (t >> 3)) * K + gch * 8;
    // A gather: row=t>>2, 16 cols from (t&3)*16; chunks c0=(t&3)*2, c0+1
    int arow = t >> 2;
    int tok = seqp[m0 + arow];
    const float* ep = embed + (size_t)tok * H + (t & 3) * 16;
    int aoff0 = arow * 64 + ((((t & 3) * 2) ^ (arow & 7)) << 3);
    int aoff1 = arow * 64 + (((((t & 3) * 2) | 1) ^ (arow & 7)) << 3);

    f32x4 acc[2][4];
    #pragma unroll
    for (int i = 0; i < 2; ++i)
        #pragma unroll
        for (int j = 0; j < 4; ++j)
            acc[i][j] = (f32x4){0.f, 0.f, 0.f, 0.f};

#define FFN1_STAGE(bufi, k)                                                   \
    {                                                                         \
        GLDS16(bp + (k),           &Bl[bufi][wid * 512]);                     \
        GLDS16(bp + (k) + 32 * K,  &Bl[bufi][wid * 512 + 2048]);              \
        GLDS16(bp + (k) + 64 * K,  &Bl[bufi][wid * 512 + 4096]);              \
        GLDS16(bp + (k) + 96 * K,  &Bl[bufi][wid * 512 + 6144]);              \
        float4 f0 = *(const float4*)(ep + (k));                               \
        float4 f1 = *(const float4*)(ep + (k) + 4);                           \
        float4 f2 = *(const float4*)(ep + (k) + 8);                           \
        float4 f3 = *(const float4*)(ep + (k) + 12);                          \
        short8 s0, s1;                                                        \
        s0[0] = (short)f2bf(f0.x); s0[1] = (short)f2bf(f0.y);                 \
        s0[2] = (short)f2bf(f0.z); s0[3] = (short)f2bf(f0.w);                 \
        s0[4] = (short)f2bf(f1.x); s0[5] = (short)f2bf(f1.y);                 \
        s0[6] = (short)f2bf(f1.z); s0[7] = (short)f2bf(f1.w);                 \
        s1[0] = (short)f2bf(f2.x); s1[1] = (short)f2bf(f2.y);                 \
        s1[2] = (short)f2bf(f2.z); s1[3] = (short)f2bf(f2.w);                 \
        s1[4] = (short)f2bf(f3.x); s1[5] = (short)f2bf(f3.y);                 \
        s1[6] = (short)f2bf(f3.z); s1[7] = (short)f2bf(f3.w);                 \
        *(short8*)&Al[bufi][aoff0] = s0;                                      \
        *(short8*)&Al[bufi][aoff1] = s1;                                      \
    }

    int nk = K / 64;
    FFN1_STAGE(0, 0);
    __syncthreads();
    for (int ks = 0; ks < nk; ++ks) {
        int cur = ks & 1;
        if (ks + 1 < nk) FFN1_STAGE(cur ^ 1, (ks + 1) * 64);
        #pragma unroll
        for (int kc = 0; kc < 2; ++kc) {
            int sl = (((kc << 2) | quad) ^ (lid & 7)) << 3;
            short8 af[2], bfr[4];
            #pragma unroll
            for (int i = 0; i < 2; ++i)
                af[i] = *(const short8*)&Al[cur][(wm + i * 16 + lid) * 64 + sl];
            #pragma unroll
            for (int i = 0; i < 4; ++i)
                bfr[i] = *(const short8*)&Bl[cur][(wn + i * 16 + lid) * 64 + sl];
            #pragma unroll
            for (int mt = 0; mt < 2; ++mt)
                #pragma unroll
                for (int nt = 0; nt < 4; ++nt)
                    acc[mt][nt] = __builtin_amdgcn_mfma_f32_16x16x32_bf16(
                        af[mt], bfr[nt], acc[mt][nt], 0, 0, 0);
        }
        __syncthreads();
    }
#undef FFN1_STAGE
    #pragma unroll
    for (int mt = 0; mt < 2; ++mt)
        #pragma unroll
        for (int nt = 0; nt < 4; ++nt)
            #pragma unroll
            for (int rg = 0; rg < 4; ++rg) {
                int row = m0 + wm + mt * 16 + quad * 4 + rg;
                int col = n0 + wn + nt * 16 + lid;
                float v = fmaxf(acc[mt][nt][rg] + bias[col], 0.f);
                Cout[(size_t)row * N + col] = f2bf(v);
            }
}

// ======================= GEMM 2: x = t1 @ w2 + b2 + gather(embed,seq) =============
__global__ __launch_bounds__(256) void gemm_ffn2(
        const ushort_t* __restrict__ A, const ushort_t* __restrict__ Bt,
        const float* __restrict__ bias, const int* __restrict__ seqp,
        const float* __restrict__ embed, ushort_t* __restrict__ Cout,
        int N, int K) {
    __shared__ __align__(16) ushort_t Al[2][4096];
    __shared__ __align__(16) ushort_t Bl[2][8192];
    int t = threadIdx.x;
    int m0 = blockIdx.y * 64, n0 = blockIdx.x * 128;
    int lane = t & 63, wid = t >> 6;
    int wm = (wid & 1) * 32, wn = (wid >> 1) * 64;
    int lid = lane & 15, quad = lane >> 4;

    int gch = (t & 7) ^ ((t >> 3) & 7);
    const ushort_t* ap = A + (size_t)(m0 + (t >> 3)) * K + gch * 8;
    const ushort_t* bp = Bt + (size_t)(n0 + (t >> 3)) * K + gch * 8;

    f32x4 acc[2][4];
    #pragma unroll
    for (int i = 0; i < 2; ++i)
        #pragma unroll
        for (int j = 0; j < 4; ++j)
            acc[i][j] = (f32x4){0.f, 0.f, 0.f, 0.f};

#define G2_STAGE(bufi, k)                                                     \
    {                                                                         \
        GLDS16(ap + (k),           &Al[bufi][wid * 512]);                     \
        GLDS16(ap + (k) + 32 * K,  &Al[bufi][wid * 512 + 2048]);              \
        GLDS16(bp + (k),           &Bl[bufi][wid * 512]);                     \
        GLDS16(bp + (k) + 32 * K,  &Bl[bufi][wid * 512 + 2048]);              \
        GLDS16(bp + (k) + 64 * K,  &Bl[bufi][wid * 512 + 4096]);              \
        GLDS16(bp + (k) + 96 * K,  &Bl[bufi][wid * 512 + 6144]);              \
    }

    int nk = K / 64;
    G2_STAGE(0, 0);
    __syncthreads();
    for (int ks = 0; ks < nk; ++ks) {
        int cur = ks & 1;
        if (ks + 1 < nk) G2_STAGE(cur ^ 1, (ks + 1) * 64);
        #pragma unroll
        for (int kc = 0; kc < 2; ++kc) {
            int sl = (((kc << 2) | quad) ^ (lid & 7)) << 3;
            short8 af[2], bfr[4];
            #pragma unroll
            for (int i = 0; i < 2; ++i)
                af[i] = *(const short8*)&Al[cur][(wm + i * 16 + lid) * 64 + sl];
            #pragma unroll
            for (int i = 0; i < 4; ++i)
                bfr[i] = *(const short8*)&Bl[cur][(wn + i * 16 + lid) * 64 + sl];
            #pragma unroll
            for (int mt = 0; mt < 2; ++mt)
                #pragma unroll
                for (int nt = 0; nt < 4; ++nt)
                    acc[mt][nt] = __builtin_amdgcn_mfma_f32_16x16x32_bf16(
                        af[mt], bfr[nt], acc[mt][nt], 0, 0, 0);
        }
        __syncthreads();
    }
#undef G2_STAGE
    #pragma unroll
    for (int mt = 0; mt < 2; ++mt)
        #pragma unroll
        for (int rg = 0; rg < 4; ++rg) {
            int row = m0 + wm + mt * 16 + quad * 4 + rg;
            int tok = seqp[row];
            const float* erow = embed + (size_t)tok * H;
            #pragma unroll
            for (int nt = 0; nt < 4; ++nt) {
                int col = n0 + wn + nt * 16 + lid;
                float v = acc[mt][nt][rg] + bias[col] + erow[col];
                Cout[(size_t)row * N + col] = f2bf(v);
            }
        }
}

// ====== fused projections: [ks|ke] = h @ [sem_w|epi_w] + b  (Bt rows concat) ======
__global__ __launch_bounds__(256) void gemm_proj(
        const ushort_t* __restrict__ A, const ushort_t* __restrict__ Bt,
        const float* __restrict__ biasS, const float* __restrict__ biasE,
        ushort_t* __restrict__ outS, ushort_t* __restrict__ outE, int K) {
    __shared__ __align__(16) ushort_t Al[2][4096];
    __shared__ __align__(16) ushort_t Bl[2][8192];
    int t = threadIdx.x;
    int m0 = blockIdx.y * 64, n0 = blockIdx.x * 128;    // n0 in 0..384
    int lane = t & 63, wid = t >> 6;
    int wm = (wid & 1) * 32, wn = (wid >> 1) * 64;
    int lid = lane & 15, quad = lane >> 4;

    int gch = (t & 7) ^ ((t >> 3) & 7);
    const ushort_t* ap = A + (size_t)(m0 + (t >> 3)) * K + gch * 8;
    const ushort_t* bp = Bt + (size_t)(n0 + (t >> 3)) * K + gch * 8;

    f32x4 acc[2][4];
    #pragma unroll
    for (int i = 0; i < 2; ++i)
        #pragma unroll
        for (int j = 0; j < 4; ++j)
            acc[i][j] = (f32x4){0.f, 0.f, 0.f, 0.f};

#define GP_STAGE(bufi, k)                                                     \
    {                                                                         \
        GLDS16(ap + (k),           &Al[bufi][wid * 512]);                     \
        GLDS16(ap + (k) + 32 * K,  &Al[bufi][wid * 512 + 2048]);              \
        GLDS16(bp + (k),           &Bl[bufi][wid * 512]);                     \
        GLDS16(bp + (k) + 32 * K,  &Bl[bufi][wid * 512 + 2048]);              \
        GLDS16(bp + (k) + 64 * K,  &Bl[bufi][wid * 512 + 4096]);              \
        GLDS16(bp + (k) + 96 * K,  &Bl[bufi][wid * 512 + 6144]);              \
    }

    int nk = K / 64;
    GP_STAGE(0, 0);
    __syncthreads();
    for (int ks = 0; ks < nk; ++ks) {
        int cur = ks & 1;
        if (ks + 1 < nk) GP_STAGE(cur ^ 1, (ks + 1) * 64);
        #pragma unroll
        for (int kc = 0; kc < 2; ++kc) {
            int sl = (((kc << 2) | quad) ^ (lid & 7)) << 3;
            short8 af[2], bfr[4];
            #pragma unroll
            for (int i = 0; i < 2; ++i)
                af[i] = *(const short8*)&Al[cur][(wm + i * 16 + lid) * 64 + sl];
            #pragma unroll
            for (int i = 0; i < 4; ++i)
                bfr[i] = *(const short8*)&Bl[cur][(wn + i * 16 + lid) * 64 + sl];
            #pragma unroll
            for (int mt = 0; mt < 2; ++mt)
                #pragma unroll
                for (int nt = 0; nt < 4; ++nt)
                    acc[mt][nt] = __builtin_amdgcn_mfma_f32_16x16x32_bf16(
                        af[mt], bfr[nt], acc[mt][nt], 0, 0, 0);
        }
        __syncthreads();
    }
#undef GP_STAGE
    #pragma unroll
    for (int mt = 0; mt < 2; ++mt)
        #pragma unroll
        for (int nt = 0; nt < 4; ++nt)
            #pragma unroll
            for (int rg = 0; rg < 4; ++rg) {
                int row = m0 + wm + mt * 16 + quad * 4 + rg;
                int col = n0 + wn + nt * 16 + lid;   // wave-uniform half selection
                if (col < 256)
                    outS[(size_t)row * HALFD + col] = f2bf(acc[mt][nt][rg] + biasS[col]);
                else
                    outE[(size_t)row * HALFD + col - 256] =
                        f2bf(acc[mt][nt][rg] + biasE[col - 256]);
            }
}

// ---------------- LayerNorm over H=512 (bf16 in-place), one wave per row ----------
__global__ void ln_kernel(ushort_t* X, const float* __restrict__ g,
                          const float* __restrict__ bta) {
    int row = blockIdx.x * 4 + (threadIdx.x >> 6);
    int lane = threadIdx.x & 63;
    ushort_t* xr = X + (size_t)row * H + lane * 8;
    short8 xv = *(short8*)xr;
    float x[8];
    #pragma unroll
    for (int j = 0; j < 8; ++j) x[j] = bf2f((ushort_t)xv[j]);
    float s = 0.f, ss = 0.f;
    #pragma unroll
    for (int j = 0; j < 8; ++j) { s += x[j]; ss += x[j] * x[j]; }
    #pragma unroll
    for (int d = 1; d < 64; d <<= 1) { s += __shfl_xor(s, d); ss += __shfl_xor(ss, d); }
    float mu = s * (1.f / 512.f);
    float var = ss * (1.f / 512.f) - mu * mu;
    float rstd = rsqrtf(var + 1e-5f);
    float4 g0 = *(const float4*)(g + lane * 8);
    float4 g1 = *(const float4*)(g + lane * 8 + 4);
    float4 b0 = *(const float4*)(bta + lane * 8);
    float4 b1 = *(const float4*)(bta + lane * 8 + 4);
    float gg[8] = {g0.x, g0.y, g0.z, g0.w, g1.x, g1.y, g1.z, g1.w};
    float bb[8] = {b0.x, b0.y, b0.z, b0.w, b1.x, b1.y, b1.z, b1.w};
    short8 o;
    #pragma unroll
    for (int j = 0; j < 8; ++j)
        o[j] = (short)f2bf((x[j] - mu) * rstd * gg[j] + bb[j]);
    *(short8*)xr = o;
}

// ---------------- beta[row] = sum(k^2) + 1e-6 (bf16 input), one wave per row ------
__global__ void beta_kernel(const ushort_t* __restrict__ k, float* __restrict__ beta) {
    int row = blockIdx.x * 4 + (threadIdx.x >> 6);
    int lane = threadIdx.x & 63;
    ushort4 a = *(const ushort4*)(k + (size_t)row * HALFD + lane * 4);
    float ax = bf2f(a.x), ay = bf2f(a.y), az = bf2f(a.z), aw = bf2f(a.w);
    float s = ax * ax + ay * ay + az * az + aw * aw;
    #pragma unroll
    for (int d = 1; d < 64; d <<= 1) s += __shfl_xor(s, d);
    if (lane == 0) beta[row] = s + 1e-6f;
}

// ================= chunked delta-rule: Tinv precompute (barrier-free fsub) ========
__global__ __launch_bounds__(256) void tinv_kernel(
        const ushort_t* __restrict__ ks, const ushort_t* __restrict__ ke,
        const float* __restrict__ beta_s, const float* __restrict__ beta_e,
        ushort_t* __restrict__ Dg) {
    __shared__ __align__(16) ushort_t Kl[64][280];
    __shared__ __align__(16) ushort_t LmT[4][64][66];   // LmT[pp][j][i] = L[i][j]
    __shared__ float betsl[4][64];

    int t = threadIdx.x;
    int lane = t & 63, wv = t >> 6;
    int lid = lane & 15, quad = lane >> 4;
    int blk0 = blockIdx.x * 4;
    const float invL = 1.0f / 1024.0f;

    for (int pp = 0; pp < 4; ++pp) {
        int p = blk0 + pp;
        int ch = p & 15, bm = p >> 4;
        int mat = bm & 1, b = bm >> 1;
        const ushort_t* Kp = (mat ? ke : ks) + ((size_t)b * LSEQ + ch * 64) * HALFD;
        const float* Bp = (mat ? beta_e : beta_s) + (size_t)b * LSEQ + ch * 64;

        __syncthreads();                    // Kl free (prev pp's MFMA reads done)
        {   // stage K chunk (64 x 256 bf16)
            int j = t >> 2, c0 = (t & 3) * 64;
            const ushort_t* src = Kp + (size_t)j * HALFD + c0;
            #pragma unroll
            for (int x = 0; x < 8; ++x)
                *(short8*)&Kl[j][c0 + x * 8] = *(const short8*)(src + x * 8);
        }
        if (t < 64) betsl[pp][t] = Bp[t];
        __syncthreads();

        // G = K K^T; wave wv owns rows wv*16..+16
        f32x4 g[4];
        #pragma unroll
        for (int i = 0; i < 4; ++i) g[i] = (f32x4){0.f, 0.f, 0.f, 0.f};
        #pragma unroll
        for (int kc = 0; kc < 8; ++kc) {
            short8 af = *(const short8*)&Kl[wv * 16 + lid][kc * 32 + quad * 8];
            #pragma unroll
            for (int nt = 0; nt < 4; ++nt) {
                short8 bq = *(const short8*)&Kl[nt * 16 + lid][kc * 32 + quad * 8];
                g[nt] = __builtin_amdgcn_mfma_f32_16x16x32_bf16(af, bq, g[nt], 0, 0, 0);
            }
        }
        #pragma unroll
        for (int nt = 0; nt < 4; ++nt)
            #pragma unroll
            for (int rg = 0; rg < 4; ++rg) {
                int i = wv * 16 + quad * 4 + rg;     // row of L
                int j = nt * 16 + lid;               // col of L
                int s = ch * 64 + i;
                float wgt = mat ? (float)(s + 1) * invL : 1.0f;
                if (s >= 1023) wgt = 0.f;            // padding step
                float wb = wgt / betsl[pp][i];
                LmT[pp][j][i] = f2bf((j < i) ? g[nt][rg] * wb : 0.f);
            }
    }
    __syncthreads();                        // all LmT ready

    // barrier-free fsub: wave wv owns problem blk0+wv; lane owns column `lane`
    const ushort_t (*Lp)[66] = LmT[wv];
    float a[64];
    #pragma unroll
    for (int x = 0; x < 32; ++x) {          // a[i] = -L[i][lane] = -LmT[lane][i]
        uint_t u = *(const uint_t*)&Lp[lane][x * 2];
        a[x * 2]     = -bflo(u);
        a[x * 2 + 1] = -bfhi(u);
    }
    #pragma unroll
    for (int j = 0; j < 63; ++j) {
        float dj = a[j];
        const ushort_t* rowj = Lp[j];
        #pragma unroll
        for (int ii = (j + 1) & ~1; ii < 64; ii += 2) {
            uint_t u = *(const uint_t*)&rowj[ii];    // wave-uniform broadcast
            if (ii > j) a[ii] -= bflo(u) * dj;
            a[ii + 1]        -= bfhi(u) * dj;
        }
    }
    size_t pbase = (size_t)(blk0 + wv) * 4096;
    #pragma unroll
    for (int i = 0; i < 64; ++i)
        Dg[pbase + (size_t)i * 64 + lane] = f2bf(a[i]);
}

// ================= chunked delta-rule scan (MFMA) — r3 version (proven ~145 us) ===
__global__ __launch_bounds__(512) void scan_kernel(
        const ushort_t* __restrict__ ks, const ushort_t* __restrict__ ke,
        const float* __restrict__ beta_s, const float* __restrict__ beta_e,
        const ushort_t* __restrict__ Dg, float* __restrict__ c) {
    int blk = blockIdx.x;
    int b = blk >> 2, mat = (blk >> 1) & 1, half = blk & 1;
    const ushort_t* Kp = (mat ? ke : ks) + (size_t)b * LSEQ * HALFD;
    const float* Bp = (mat ? beta_e : beta_s) + (size_t)b * LSEQ;
    const ushort_t* Dp = Dg + (size_t)(b * 2 + mat) * 16 * 4096;

    __shared__ __align__(16) ushort_t Kl[64][264];      // K chunk [j][c]
    __shared__ __align__(16) ushort_t MK[33792];        // union: Ml[128][264] | Kt[256][72]
    __shared__ __align__(16) ushort_t RHSl[128][72];    // RHS^T [r][j']
    __shared__ __align__(16) ushort_t Ul[128][72];      // U^T [r][j]
    __shared__ __align__(16) ushort_t Dl[64][72];       // Tinv - I [j][j']
    __shared__ float bets[LSEQ];

    ushort_t (*Ml)[264] = (ushort_t(*)[264])MK;
    ushort_t (*Kt)[72]  = (ushort_t(*)[72])MK;

    int t = threadIdx.x;
    int lane = t & 63, wid = t >> 6;
    int lid = lane & 15, quad = lane >> 4;
    int wm  = (wid & 1) * 64, wn  = (wid >> 1) * 64;    // GEMM3/M org: 128x256 tile
    int wm1 = (wid & 1) * 64, wn1 = (wid >> 1) * 16;    // GEMM1/2 org: 128x64 tile

    #pragma unroll
    for (int i = 0; i < 2; ++i) bets[t + i * 512] = Bp[t + i * 512];

    f32x4 acc[4][4];
    #pragma unroll
    for (int i = 0; i < 4; ++i)
        #pragma unroll
        for (int j = 0; j < 4; ++j)
            acc[i][j] = (f32x4){0.f, 0.f, 0.f, 0.f};

    // K staging: thread t -> row sj, 4 x short8 at cols (t&7)*8 + x*64 (coalesced)
    int sj = t >> 3, scb = (t & 7) * 8;
    short8 pf[4];
    {
        const ushort_t* kr = Kp + (size_t)sj * HALFD + scb;
        #pragma unroll
        for (int x = 0; x < 4; ++x) pf[x] = *(const short8*)(kr + x * 64);
    }
    short8 dpf = *(const short8*)(Dp + t * 8);
    const float invL = 1.0f / 1024.0f;

    for (int ch = 0; ch < 16; ++ch) {
        __syncthreads();                       // F: prior-chunk LDS reads done
        #pragma unroll
        for (int x = 0; x < 4; ++x) *(short8*)&Kl[sj][scb + x * 64] = pf[x];
        *(short8*)&Dl[t >> 3][(t & 7) * 8] = dpf;
        // M_hi -> Ml
        #pragma unroll
        for (int mt = 0; mt < 4; ++mt)
            #pragma unroll
            for (int nt = 0; nt < 4; ++nt)
                #pragma unroll
                for (int rg = 0; rg < 4; ++rg)
                    Ml[wm + mt * 16 + quad * 4 + rg][wn + nt * 16 + lid] =
                        f2bf(acc[mt][nt][rg]);
        // prefetch next chunk
        int nch = (ch + 1 < 16) ? ch + 1 : 15;
        {
            const ushort_t* kr = Kp + ((size_t)nch * 64 + sj) * HALFD + scb;
            #pragma unroll
            for (int x = 0; x < 4; ++x) pf[x] = *(const short8*)(kr + x * 64);
            dpf = *(const short8*)(Dp + (size_t)nch * 4096 + t * 8);
        }
        __syncthreads();                       // A

        // GEMM1 hi: P0^T[r,i] += sum_c Mhi[r,c] K[i,c]
        f32x4 p0[4];
        #pragma unroll
        for (int i = 0; i < 4; ++i) p0[i] = (f32x4){0.f, 0.f, 0.f, 0.f};
        #pragma unroll
        for (int kc = 0; kc < 8; ++kc) {
            short8 bq = *(const short8*)&Kl[wn1 + lid][kc * 32 + quad * 8];
            #pragma unroll
            for (int mt = 0; mt < 4; ++mt) {
                short8 aq = *(const short8*)&Ml[wm1 + mt * 16 + lid][kc * 32 + quad * 8];
                p0[mt] = __builtin_amdgcn_mfma_f32_16x16x32_bf16(aq, bq, p0[mt], 0, 0, 0);
            }
        }
        __syncthreads();                       // B: Ml(hi) reads done
        // M_lo -> Ml
        #pragma unroll
        for (int mt = 0; mt < 4; ++mt)
            #pragma unroll
            for (int nt = 0; nt < 4; ++nt)
                #pragma unroll
                for (int rg = 0; rg < 4; ++rg) {
                    float v = acc[mt][nt][rg];
                    Ml[wm + mt * 16 + quad * 4 + rg][wn + nt * 16 + lid] =
                        f2bf(v - bf2f(f2bf(v)));
                }
        __syncthreads();                       // C
        // GEMM1 lo
        #pragma unroll
        for (int kc = 0; kc < 8; ++kc) {
            short8 bq = *(const short8*)&Kl[wn1 + lid][kc * 32 + quad * 8];
            #pragma unroll
            for (int mt = 0; mt < 4; ++mt) {
                short8 aq = *(const short8*)&Ml[wm1 + mt * 16 + lid][kc * 32 + quad * 8];
                p0[mt] = __builtin_amdgcn_mfma_f32_16x16x32_bf16(aq, bq, p0[mt], 0, 0, 0);
            }
        }
        // RHS: rhs[r,i] = w_i*k_i[hr] - (w_i/beta_i)*P0^T[r,i]
        int iB = wn1 + lid;
        int s = ch * 64 + iB;
        float wgt = mat ? (float)(s + 1) * invL : 1.0f;
        if (s >= 1023) wgt = 0.f;
        float wb = wgt / bets[s];
        float rhsf[4][4];
        #pragma unroll
        for (int mt = 0; mt < 4; ++mt)
            #pragma unroll
            for (int rg = 0; rg < 4; ++rg) {
                int r = wm1 + mt * 16 + quad * 4 + rg;
                float kv = bf2f(Kl[iB][half * 128 + r]);
                float rv = wgt * kv - wb * p0[mt][rg];
                rhsf[mt][rg] = rv;
                RHSl[r][iB] = f2bf(rv);
            }
        __syncthreads();                       // D: RHS ready; Ml region free

        // build Kt[c][j] = K[j][c] into the (free) Ml region
        {
            int c0 = wid * 32;
            #pragma unroll
            for (int rr = 0; rr < 4; ++rr) {
                short8 kv8 = *(const short8*)&Kl[lane][c0 + rr * 8];
                #pragma unroll
                for (int x = 0; x < 8; ++x)
                    Kt[c0 + rr * 8 + x][lane] = (ushort_t)kv8[x];
            }
        }
        // GEMM2: corr[r,j] = sum_j' RHS^T[r,j'] * D[j,j']
        f32x4 uf[4];
        #pragma unroll
        for (int i = 0; i < 4; ++i) uf[i] = (f32x4){0.f, 0.f, 0.f, 0.f};
        #pragma unroll
        for (int kc = 0; kc < 2; ++kc) {
            short8 bq = *(const short8*)&Dl[wn1 + lid][kc * 32 + quad * 8];
            #pragma unroll
            for (int mt = 0; mt < 4; ++mt) {
                short8 aq = *(const short8*)&RHSl[wm1 + mt * 16 + lid][kc * 32 + quad * 8];
                uf[mt] = __builtin_amdgcn_mfma_f32_16x16x32_bf16(aq, bq, uf[mt], 0, 0, 0);
            }
        }
        // u = corr + RHS (exact fp32 RHS from regs; frag positions identical)
        #pragma unroll
        for (int mt = 0; mt < 4; ++mt)
            #pragma unroll
            for (int rg = 0; rg < 4; ++rg) {
                int r = wm1 + mt * 16 + quad * 4 + rg;
                Ul[r][wn1 + lid] = f2bf(uf[mt][rg] + rhsf[mt][rg]);
            }
        __syncthreads();                       // E: Kt + U(hi) ready
        // GEMM3 hi: M += Uhi^T * K
        #pragma unroll
        for (int kc = 0; kc < 2; ++kc) {
            short8 bq4[4];
            #pragma unroll
            for (int nt = 0; nt < 4; ++nt)
                bq4[nt] = *(const short8*)&Kt[wn + nt * 16 + lid][kc * 32 + quad * 8];
            #pragma unroll
            for (int mt = 0; mt < 4; ++mt) {
                short8 aq = *(const short8*)&Ul[wm + mt * 16 + lid][kc * 32 + quad * 8];
                #pragma unroll
                for (int nt = 0; nt < 4; ++nt)
                    acc[mt][nt] = __builtin_amdgcn_mfma_f32_16x16x32_bf16(
                        aq, bq4[nt], acc[mt][nt], 0, 0, 0);
            }
        }
        __syncthreads();                       // E2: Ul(hi) reads done
        #pragma unroll
        for (int mt = 0; mt < 4; ++mt)
            #pragma unroll
            for (int rg = 0; rg < 4; ++rg) {
                int r = wm1 + mt * 16 + quad * 4 + rg;
                float u = uf[mt][rg] + rhsf[mt][rg];
                Ul[r][wn1 + lid] = f2bf(u - bf2f(f2bf(u)));
            }
        __syncthreads();                       // E3
        // GEMM3 lo
        #pragma unroll
        for (int kc = 0; kc < 2; ++kc) {
            short8 bq4[4];
            #pragma unroll
            for (int nt = 0; nt < 4; ++nt)
                bq4[nt] = *(const short8*)&Kt[wn + nt * 16 + lid][kc * 32 + quad * 8];
            #pragma unroll
            for (int mt = 0; mt < 4; ++mt) {
                short8 aq = *(const short8*)&Ul[wm + mt * 16 + lid][kc * 32 + quad * 8];
                #pragma unroll
                for (int nt = 0; nt < 4; ++nt)
                    acc[mt][nt] = __builtin_amdgcn_mfma_f32_16x16x32_bf16(
                        aq, bq4[nt], acc[mt][nt], 0, 0, 0);
            }
        }
    }

    // final matvec: c[hr] = sum_c M[hr,c] * k[1023][c]  (k[1023] = Kl row 63)
    __syncthreads();
    float* vsc = (float*)RHSl;                 // 4 x 128 scratch
    float kvv[4];
    #pragma unroll
    for (int nt = 0; nt < 4; ++nt)
        kvv[nt] = bf2f(Kl[63][wn + nt * 16 + lid]);
    #pragma unroll
    for (int mt = 0; mt < 4; ++mt)
        #pragma unroll
        for (int rg = 0; rg < 4; ++rg) {
            float p = acc[mt][0][rg] * kvv[0] + acc[mt][1][rg] * kvv[1]
                    + acc[mt][2][rg] * kvv[2] + acc[mt][3][rg] * kvv[3];
            p += __shfl_xor(p, 1); p += __shfl_xor(p, 2);
            p += __shfl_xor(p, 4); p += __shfl_xor(p, 8);
            if (lid == 0)
                vsc[(wid >> 1) * 128 + wm + mt * 16 + quad * 4 + rg] = p;
        }
    __syncthreads();
    if (t < 128) {
        float sum = vsc[t] + vsc[128 + t] + vsc[256 + t] + vsc[384 + t];
        c[(size_t)b * 512 + mat * 256 + half * 128 + t] = sum;
    }
}

// ---------------- output GEMM: out[64x32000] = c[64x512] @ W[512x32000] + b -------
__global__ __launch_bounds__(512) void out_gemm(
        const float* __restrict__ c, const float* __restrict__ W,
        const float* __restrict__ bias, float* __restrict__ out) {
    __shared__ __align__(16) float cl[16][512];
    int t = threadIdx.x;
    int lane = t & 63, w = t >> 6;                    // 8 waves
    int cb = blockIdx.x * 256;                        // 125*256 = 32000
    int rb = blockIdx.y * 16;                         // 4*16 = 64 rows

    #pragma unroll
    for (int i = 0; i < 4; ++i) {
        int idx = t + i * 512;                        // float4 index
        int row = idx >> 7, c4 = (idx & 127) * 4;
        *(float4*)&cl[row][c4] = *(const float4*)(c + (size_t)(rb + row) * 512 + c4);
    }
    __syncthreads();

    const float* wp = W + cb + lane * 4;
    int r0 = w * 2;
    f32x4 a0 = (f32x4){0.f, 0.f, 0.f, 0.f};
    f32x4 a1 = (f32x4){0.f, 0.f, 0.f, 0.f};

    #pragma unroll 2
    for (int k = 0; k < 512; k += 4) {
        f32x4 w0 = *(const f32x4*)(wp + (size_t)(k + 0) * V);
        f32x4 w1 = *(const f32x4*)(wp + (size_t)(k + 1) * V);
        f32x4 w2 = *(const f32x4*)(wp + (size_t)(k + 2) * V);
        f32x4 w3 = *(const f32x4*)(wp + (size_t)(k + 3) * V);
        f32x4 ca = *(const f32x4*)&cl[r0][k];
        f32x4 cb4 = *(const f32x4*)&cl[r0 + 1][k];
        a0 += ca[0] * w0; a0 += ca[1] * w1; a0 += ca[2] * w2; a0 += ca[3] * w3;
        a1 += cb4[0] * w0; a1 += cb4[1] * w1; a1 += cb4[2] * w2; a1 += cb4[3] * w3;
    }
    f32x4 bv = *(const f32x4*)(bias + cb + lane * 4);
    *(f32x4*)(out + (size_t)(rb + r0) * V + cb + lane * 4) = a0 + bv;
    *(f32x4*)(out + (size_t)(rb + r0 + 1) * V + cb + lane * 4) = a1 + bv;
}

// ---------------- launch ----------------------------------------------------------
extern "C" void kernel_launch(void* const* d_in, const int* in_sizes, int n_in,
                              void* d_out, int out_size, void* d_ws, size_t ws_size,
                              hipStream_t stream) {
    const int*   seq    = (const int*)d_in[0];
    const float* embed  = (const float*)d_in[1];
    const float* ff_w1  = (const float*)d_in[2];
    const float* ff_b1  = (const float*)d_in[3];
    const float* ff_w2  = (const float*)d_in[4];
    const float* ff_b2  = (const float*)d_in[5];
    const float* ln_g   = (const float*)d_in[6];
    const float* ln_b   = (const float*)d_in[7];
    const float* sem_w  = (const float*)d_in[8];
    const float* sem_b  = (const float*)d_in[9];
    const float* epi_w  = (const float*)d_in[10];
    const float* epi_b  = (const float*)d_in[11];
    const float* out_w  = (const float*)d_in[12];
    const float* out_b  = (const float*)d_in[13];
    float* outp = (float*)d_out;

    const int ML = BB * LSEQ;                         // 65536 rows
    int RCH;
    if      (ws_size >= 271712256ull) RCH = 65536;    // 1 chunk
    else if (ws_size >= 120717312ull) RCH = 16384;    // 4 chunks
    else                              RCH = 8192;     // 8 chunks (95,551,488 proven)

    char* w = (char*)d_ws;
    size_t off = 0;
    ushort_t* ks_bf = (ushort_t*)(w + off); off += 33554432;          // 65536x256 bf16
    ushort_t* ke_bf = (ushort_t*)(w + off); off += 33554432;
    ushort_t* ebc   = (ushort_t*)(w + off); off += (size_t)RCH * 512 * 2;   // x/h chunk
    ushort_t* t1c   = (ushort_t*)(w + off); off += (size_t)RCH * 1024 * 2;  // relu chunk
    ushort_t* w1t   = (ushort_t*)(w + off); off += 1048576;
    ushort_t* w2t   = (ushort_t*)(w + off); off += 1048576;
    ushort_t* semt  = (ushort_t*)(w + off); off += 262144;            // semt|epit adjacent
    ushort_t* epit  = (ushort_t*)(w + off); off += 262144;
    float*    bet_s = (float*)(w + off);    off += 262144;
    float*    bet_e = (float*)(w + off);    off += 262144;
    float*    cbuf  = (float*)(w + off);    off += 131072;
    // Tinv-I storage (2048 x 64 x 64 bf16 = 16.8 MB) reuses encoder chunk region.
    ushort_t* Dbuf  = ebc;
    (void)t1c;

    // weight prep (bf16 + transpose)
    transpose_cvt<<<dim3(1024 / 32, 512 / 32), 256, 0, stream>>>(ff_w1, w1t, 512, 1024);
    transpose_cvt<<<dim3(512 / 32, 1024 / 32), 256, 0, stream>>>(ff_w2, w2t, 1024, 512);
    transpose_cvt<<<dim3(256 / 32, 512 / 32), 256, 0, stream>>>(sem_w, semt, 512, 256);
    transpose_cvt<<<dim3(256 / 32, 512 / 32), 256, 0, stream>>>(epi_w, epit, 512, 256);

    // encoder, chunked over rows to bound workspace (64-row tiles, 2-phase pipeline)
    for (int cc = 0; cc < ML / RCH; ++cc) {
        int c0 = cc * RCH;
        gemm_ffn1<<<dim3(1024 / 128, RCH / 64), 256, 0, stream>>>(
            seq + c0, embed, w1t, ff_b1, t1c, 1024, 512);
        gemm_ffn2<<<dim3(512 / 128, RCH / 64), 256, 0, stream>>>(
            t1c, w2t, ff_b2, seq + c0, embed, ebc, 512, 1024);
        ln_kernel<<<RCH / 4, 256, 0, stream>>>(ebc, ln_g, ln_b);  // h, in-place
        gemm_proj<<<dim3(512 / 128, RCH / 64), 256, 0, stream>>>(
            ebc, semt, sem_b, epi_b,
            ks_bf + (size_t)c0 * HALFD, ke_bf + (size_t)c0 * HALFD, 512);
    }

    beta_kernel<<<ML / 4, 256, 0, stream>>>(ks_bf, bet_s);
    beta_kernel<<<ML / 4, 256, 0, stream>>>(ke_bf, bet_e);

    tinv_kernel<<<512, 256, 0, stream>>>(ks_bf, ke_bf, bet_s, bet_e, Dbuf);
    scan_kernel<<<256, 512, 0, stream>>>(ks_bf, ke_bf, bet_s, bet_e, Dbuf, cbuf);

    out_gemm<<<dim3(125, 4), 512, 0, stream>>>(cbuf, out_w, out_b, outp);
}